// Round 2
// baseline (3187.246 us; speedup 1.0000x reference)
//
#include <hip/hip_runtime.h>
#include <math.h>

#define N_TOTAL 32768
#define N0 8192
#define N1 1024
#define KNB 8
#define C_IN 128
#define C_H 64
#define COS_T 0.999f
#define NEG_INF -1e30f
#define GRID 1024
#define BLOCK 256

struct MegaParams {
    const float* feat;
    const float* xyz;
    const float* wsS[3];
    const float* bsS[3];
    const float* dgWs[3];
    const float* dgWn[3];
    const float* dgB[3];
    const float* dgH[3];
    const float* dgHb[3];
    const int* nb0;
    const int* ind0;
    const int* isc[2];
    float* out;
    float* xA;
    float* xB;
    float* s0;
    float* sbr;
    float* xyz0;
    int* anchor;
    int* indb;
    int* nbb;
    unsigned* cnt;     // grid-barrier counter (memset to 0 each launch)
};

// Grid-wide barrier: monotonic counter, device(agent)-scope atomics + fences.
// Valid because all GRID blocks are co-resident (4 blocks/CU x 256 CU;
// LDS 34.8KB*4 = 139KB <= 160KB, VGPR <= 128 via __launch_bounds__(256,4)).
__device__ __forceinline__ void gbar(unsigned* cnt, unsigned target) {
    __syncthreads();
    if (threadIdx.x == 0) {
        __threadfence();  // release: make prior writes agent-visible
        __hip_atomic_fetch_add(cnt, 1u, __ATOMIC_RELEASE, __HIP_MEMORY_SCOPE_AGENT);
        while (__hip_atomic_load(cnt, __ATOMIC_ACQUIRE, __HIP_MEMORY_SCOPE_AGENT) < target) {
            __builtin_amdgcn_s_sleep(1);
        }
        __threadfence();  // acquire: invalidate caches for others' writes
    }
    __syncthreads();
}

__global__ void __launch_bounds__(BLOCK, 4) mega_kernel(MegaParams P) {
    const int blk = blockIdx.x;
    const int tid = threadIdx.x;
    const int w = tid >> 6;      // wave id 0..3
    const int lane = tid & 63;   // channel

    unsigned bt = 0;             // barrier target (block-uniform call sites only)
    auto GSYNC = [&]() { bt += GRID; gbar(P.cnt, bt); };

    __shared__ union {
        float sc[N0];                                      // 32KB (NMS score copy)
        struct { float sx[N1]; float sy[N1]; float sz[N1]; } tk;  // 12KB (topk)
        struct { float xs[4][C_H]; float ag[4][C_H]; } dg; // 2KB (dgcn)
        float col[4][C_IN];                                // 2KB (sphere)
    } u;
    __shared__ float rv[BLOCK];
    __shared__ int ri[BLOCK];
    __shared__ float psel[3];

    // ---------- sphere gather + 1x1 conv (128->64); 4 nodes/block-iteration ----------
    auto sphere = [&](int n, const int* ind, const float* W, const float* b,
                      float* xout, float* xyz0dst) {
        const int ngrp = n >> 2;
        for (int g = blk; g < ngrp; g += GRID) {
            const int j = (g << 2) + w;
            const int p = ind[j];
            u.col[w][lane]      = P.feat[(size_t)lane * N_TOTAL + p];
            u.col[w][lane + 64] = P.feat[(size_t)(lane + 64) * N_TOTAL + p];
            if (xyz0dst && lane < 3) xyz0dst[j * 3 + lane] = P.xyz[p * 3 + lane];
            __syncthreads();
            float acc = b[lane];
            const float* wr = W + lane * C_IN;
#pragma unroll 8
            for (int k = 0; k < C_IN; ++k) acc += u.col[w][k] * wr[k];
            xout[(size_t)j * C_H + lane] = acc;
            __syncthreads();
        }
    };

    // ---------- one DGCN layer; optionally fused head+sigmoid on the last ----------
    auto dgcn = [&](int n, const float* xin, const int* nb,
                    const float* Wsl, const float* Wnl, const float* bias, int l,
                    float* xout, bool last, const float* head, const float* hb,
                    float* sdst, float* odst) {
        const int ngrp = n >> 2;
        const float* Ws_ = Wsl + l * C_H * C_H;
        const float* Wn_ = Wnl + l * C_H * C_H;
        for (int g = blk; g < ngrp; g += GRID) {
            const int j = (g << 2) + w;
            float xv = xin[(size_t)j * C_H + lane];
            float a = 0.f;
#pragma unroll
            for (int t = 0; t < KNB; ++t) {
                int q = nb[j * KNB + t];
                a += xin[(size_t)q * C_H + lane];
            }
            u.dg.xs[w][lane] = xv;
            u.dg.ag[w][lane] = a * (1.0f / KNB);
            __syncthreads();
            float acc = bias[l * C_H + lane];
#pragma unroll 8
            for (int k = 0; k < C_H; ++k)
                acc += u.dg.xs[w][k] * Ws_[k * C_H + lane] + u.dg.ag[w][k] * Wn_[k * C_H + lane];
            acc = fmaxf(acc, 0.f);
            if (!last) {
                xout[(size_t)j * C_H + lane] = acc;
            } else {
                float v = acc * head[lane];
#pragma unroll
                for (int off = 32; off > 0; off >>= 1) v += __shfl_down(v, off, 64);
                if (lane == 0) {
                    float s = v + hb[0];
                    sdst[j] = s;
                    odst[j] = 1.f / (1.f + expf(-s));
                }
            }
            __syncthreads();
        }
    };

    // ---------- fused gather + per-row stable top-8 (blocks 0..383, 8 rows each) ----------
    auto topk = [&](const int* isc) {
        if (blk < 384) {
            const int b = (blk * 8) >> 10;            // branch, constant per block
            const int a = P.anchor[b];
            const int* row = isc + (size_t)a * N1;
            for (int m = tid; m < N1; m += BLOCK) {
                int pp = row[m];
                u.tk.sx[m] = P.xyz[pp * 3 + 0];
                u.tk.sy[m] = P.xyz[pp * 3 + 1];
                u.tk.sz[m] = P.xyz[pp * 3 + 2];
            }
            if (tid < 8) {
                int grow = blk * 8 + tid;
                P.indb[grow] = row[grow & (N1 - 1)];
            }
            __syncthreads();
#pragma unroll
            for (int rr = 0; rr < 2; ++rr) {
                const int grow = blk * 8 + rr * 4 + w;   // global row 0..3071
                const int r = grow & (N1 - 1);
                float rx = u.tk.sx[r], ry = u.tk.sy[r], rz = u.tk.sz[r];
                unsigned long long k[16];
#pragma unroll
                for (int t = 0; t < 16; ++t) {
                    int m = t * 64 + lane;               // lane-consecutive: conflict-free
                    float v = fabsf(rx * u.tk.sx[m] + ry * u.tk.sy[m] + rz * u.tk.sz[m]);
                    k[t] = ((unsigned long long)__float_as_uint(v) << 32)
                         | (unsigned int)(0xFFFFFFFFu - (unsigned int)m);
                }
#pragma unroll
                for (int pass = 0; pass < KNB; ++pass) {
                    unsigned long long lm = k[0];
#pragma unroll
                    for (int t = 1; t < 16; ++t) lm = (k[t] > lm) ? k[t] : lm;
#pragma unroll
                    for (int off = 1; off < 64; off <<= 1) {
                        unsigned long long o = __shfl_xor(lm, off, 64);
                        lm = (o > lm) ? o : lm;
                    }
                    if (lane == 0) {
                        int idx = (int)(0xFFFFFFFFu - (unsigned int)(lm & 0xFFFFFFFFull));
                        P.nbb[grow * KNB + pass] = b * N1 + idx;
                    }
#pragma unroll
                    for (int t = 0; t < 16; ++t) if (k[t] == lm) k[t] = 0;
                }
            }
            __syncthreads();
        }
    };

    // ================= stage 0 =================
    sphere(N0, P.ind0, P.wsS[0], P.bsS[0], P.xA, P.xyz0);
    GSYNC();
    dgcn(N0, P.xA, P.nb0, P.dgWs[0], P.dgWn[0], P.dgB[0], 0, P.xB, false, nullptr, nullptr, nullptr, nullptr);
    GSYNC();
    dgcn(N0, P.xB, P.nb0, P.dgWs[0], P.dgWn[0], P.dgB[0], 1, P.xA, false, nullptr, nullptr, nullptr, nullptr);
    GSYNC();
    dgcn(N0, P.xA, P.nb0, P.dgWs[0], P.dgWn[0], P.dgB[0], 2, P.xB, false, nullptr, nullptr, nullptr, nullptr);
    GSYNC();
    dgcn(N0, P.xB, P.nb0, P.dgWs[0], P.dgWn[0], P.dgB[0], 3, nullptr, true,
         P.dgH[0], P.dgHb[0], P.s0, P.out);
    GSYNC();

    // ---------- greedy sphere NMS, 3 peaks, block 0 only, scores in LDS ----------
    if (blk == 0) {
        for (int jj = tid; jj < N0; jj += BLOCK) u.sc[jj] = P.s0[jj];
        __syncthreads();
        for (int it = 0; it < 3; ++it) {
            float bv = -INFINITY; int bi = 0x7fffffff;
            for (int jj = tid; jj < N0; jj += BLOCK) {
                float v = u.sc[jj];
                if (v > bv) { bv = v; bi = jj; }   // strided ascending -> first max kept
            }
            rv[tid] = bv; ri[tid] = bi;
            __syncthreads();
            for (int sft = BLOCK / 2; sft > 0; sft >>= 1) {
                if (tid < sft) {
                    float v2 = rv[tid + sft]; int i2 = ri[tid + sft];
                    if (v2 > rv[tid] || (v2 == rv[tid] && i2 < ri[tid])) {
                        rv[tid] = v2; ri[tid] = i2;
                    }
                }
                __syncthreads();
            }
            int sel = ri[0];
            if (tid == 0) {
                P.anchor[it] = P.ind0[sel];
                psel[0] = P.xyz0[sel * 3 + 0];
                psel[1] = P.xyz0[sel * 3 + 1];
                psel[2] = P.xyz0[sel * 3 + 2];
            }
            __syncthreads();
            float px = psel[0], py = psel[1], pz = psel[2];
            for (int jj = tid; jj < N0; jj += BLOCK) {
                float d = fabsf(P.xyz0[jj * 3 + 0] * px + P.xyz0[jj * 3 + 1] * py
                              + P.xyz0[jj * 3 + 2] * pz);
                if (d >= COS_T) u.sc[jj] = NEG_INF;
            }
            __syncthreads();
        }
    }
    GSYNC();

    // ================= stages 1 & 2 =================
    for (int st = 1; st <= 2; ++st) {
        topk(P.isc[st - 1]);
        GSYNC();
        sphere(3 * N1, P.indb, P.wsS[st], P.bsS[st], P.xA, nullptr);
        GSYNC();
        dgcn(3 * N1, P.xA, P.nbb, P.dgWs[st], P.dgWn[st], P.dgB[st], 0, P.xB, false, nullptr, nullptr, nullptr, nullptr);
        GSYNC();
        dgcn(3 * N1, P.xB, P.nbb, P.dgWs[st], P.dgWn[st], P.dgB[st], 1, P.xA, false, nullptr, nullptr, nullptr, nullptr);
        GSYNC();
        dgcn(3 * N1, P.xA, P.nbb, P.dgWs[st], P.dgWn[st], P.dgB[st], 2, P.xB, false, nullptr, nullptr, nullptr, nullptr);
        GSYNC();
        dgcn(3 * N1, P.xB, P.nbb, P.dgWs[st], P.dgWn[st], P.dgB[st], 3, nullptr, true,
             P.dgH[st], P.dgHb[st], P.sbr, P.out + N0 + (st - 1) * 3 * N1);
        if (st == 1) {
            GSYNC();
            // per-branch argmax over sbr; blocks 0..2
            if (blk < 3) {
                float bv = -INFINITY; int bi = 0x7fffffff;
                for (int m = tid; m < N1; m += BLOCK) {
                    float v = P.sbr[blk * N1 + m];
                    if (v > bv) { bv = v; bi = m; }
                }
                rv[tid] = bv; ri[tid] = bi;
                __syncthreads();
                for (int sft = BLOCK / 2; sft > 0; sft >>= 1) {
                    if (tid < sft) {
                        float v2 = rv[tid + sft]; int i2 = ri[tid + sft];
                        if (v2 > rv[tid] || (v2 == rv[tid] && i2 < ri[tid])) {
                            rv[tid] = v2; ri[tid] = i2;
                        }
                    }
                    __syncthreads();
                }
                if (tid == 0) P.anchor[blk] = P.indb[blk * N1 + ri[0]];
            }
            GSYNC();
        }
    }
}

extern "C" void kernel_launch(void* const* d_in, const int* in_sizes, int n_in,
                              void* d_out, int out_size, void* d_ws, size_t ws_size,
                              hipStream_t stream) {
    MegaParams hp;
    hp.feat = (const float*)d_in[0];
    hp.xyz  = (const float*)d_in[1];
    hp.wsS[0] = (const float*)d_in[2];  hp.bsS[0] = (const float*)d_in[3];
    hp.wsS[1] = (const float*)d_in[4];  hp.bsS[1] = (const float*)d_in[5];
    hp.wsS[2] = (const float*)d_in[6];  hp.bsS[2] = (const float*)d_in[7];
    hp.dgWs[0] = (const float*)d_in[8];  hp.dgWn[0] = (const float*)d_in[9];
    hp.dgB[0]  = (const float*)d_in[10]; hp.dgH[0]  = (const float*)d_in[11];
    hp.dgHb[0] = (const float*)d_in[12];
    hp.dgWs[1] = (const float*)d_in[13]; hp.dgWn[1] = (const float*)d_in[14];
    hp.dgB[1]  = (const float*)d_in[15]; hp.dgH[1]  = (const float*)d_in[16];
    hp.dgHb[1] = (const float*)d_in[17];
    hp.dgWs[2] = (const float*)d_in[18]; hp.dgWn[2] = (const float*)d_in[19];
    hp.dgB[2]  = (const float*)d_in[20]; hp.dgH[2]  = (const float*)d_in[21];
    hp.dgHb[2] = (const float*)d_in[22];
    const int* edge0 = (const int*)d_in[23];
    hp.nb0  = edge0 + N0 * KNB;          // neighbor row of edge0
    hp.ind0 = (const int*)d_in[24];
    hp.isc[0] = (const int*)d_in[25];
    hp.isc[1] = (const int*)d_in[26];
    hp.out = (float*)d_out;

    // workspace layout (4B elements)
    float* fws = (float*)d_ws;
    hp.xA   = fws;                          // 8192*64
    hp.xB   = hp.xA + (size_t)N0 * C_H;     // 8192*64
    hp.s0   = hp.xB + (size_t)N0 * C_H;     // 8192
    hp.sbr  = hp.s0 + N0;                   // 3072
    hp.xyz0 = hp.sbr + 3 * N1;              // 8192*3
    hp.anchor = (int*)(hp.xyz0 + (size_t)N0 * 3);  // 4
    hp.indb   = hp.anchor + 4;              // 3072
    hp.nbb    = hp.indb + 3 * N1;           // 3072*8
    hp.cnt    = (unsigned*)(hp.nbb + 3 * N1 * KNB);

    hipMemsetAsync((void*)hp.cnt, 0, 64, stream);   // reset barrier counter (graph-safe)
    mega_kernel<<<dim3(GRID), dim3(BLOCK), 0, stream>>>(hp);
}

// Round 3
// 856.437 us; speedup vs baseline: 3.7215x; 3.7215x over previous
//
#include <hip/hip_runtime.h>
#include <math.h>

#define N_TOTAL 32768
#define N0 8192
#define N1 1024
#define KNB 8
#define C_IN 128
#define C_H 64
#define COS_T 0.999f
#define NEG_INF -1e30f
#define GRID 1024
#define BLOCK 256
#define NACT 384      // blocks that stay alive after stage 0

struct MegaParams {
    const float* feat;
    const float* xyz;
    const float* wsS[3];
    const float* bsS[3];
    const float* dgWs[3];
    const float* dgWn[3];
    const float* dgB[3];
    const float* dgH[3];
    const float* dgHb[3];
    const int* nb0;
    const int* ind0;
    const int* isc[2];
    float* out;
    float* xA;
    float* xB;
    float* s0;
    float* sbr;
    float* xyz0;
    float* featT;
    int* anchor;
    int* indb;
    int* nbb;
    unsigned* cntA;    // full-grid barrier counter (B1..B6)
    unsigned* cntB;    // 384-block barrier counter (B7..B17)
    int tr;            // 1 if featT fits in workspace
};

// Grid barrier. CRITICAL: polls are RELAXED (no per-poll buffer_inv / L2
// invalidate — that was the 180us/barrier pathology). One release fence at
// arrive, one acquire fence at exit. Valid only because all participating
// blocks are co-resident (4 blocks/CU x 256 CU; LDS ~37.4KB*4 = 150KB <= 160KB,
// VGPR <= 128 via __launch_bounds__(256,4)).
__device__ __forceinline__ void gbar(unsigned* c, unsigned target) {
    __syncthreads();
    if (threadIdx.x == 0) {
        __builtin_amdgcn_fence(__ATOMIC_RELEASE, "agent");
        __hip_atomic_fetch_add(c, 1u, __ATOMIC_RELAXED, __HIP_MEMORY_SCOPE_AGENT);
        while (__hip_atomic_load(c, __ATOMIC_RELAXED, __HIP_MEMORY_SCOPE_AGENT) < target)
            __builtin_amdgcn_s_sleep(8);
        __builtin_amdgcn_fence(__ATOMIC_ACQUIRE, "agent");
    }
    __syncthreads();
}

__global__ void __launch_bounds__(BLOCK, 4) mega_kernel(MegaParams P) {
    const int blk = blockIdx.x;
    const int tid = threadIdx.x;
    const int w = tid >> 6;      // wave id 0..3
    const int lane = tid & 63;   // channel

    __shared__ union {
        float sc[N0];                                            // 32KB   (NMS)
        struct { float wt[C_IN * 65]; float col[4][C_IN]; } sp;  // 35.3KB (sphere)
        struct { float ws[C_H * C_H]; float wn[C_H * C_H];
                 float xw[4][C_H]; float aw[4][C_H]; } dg;       // 34KB   (dgcn)
        struct { float sx[N1]; float sy[N1]; float sz[N1]; } tk; // 12KB   (topk)
    } u;
    __shared__ float rv[BLOCK];
    __shared__ int ri[BLOCK];
    __shared__ float psel[3];

    // ---- sphere: 8 nodes/block, W^T staged in LDS (pad 65: conflict-free) ----
    auto sphere = [&](const int* ind, const float* W, const float* bv, float* xout) {
        __syncthreads();                       // union handoff
        for (int i = tid; i < C_H * C_IN; i += BLOCK) {
            int c = i >> 7, k = i & 127;       // i = c*128+k; read coalesced
            u.sp.wt[k * 65 + c] = W[i];
        }
        __syncthreads();
#pragma unroll
        for (int it = 0; it < 2; ++it) {
            int j = blk * 8 + it * 4 + w;
            int p = ind[j];
            if (P.tr) {
                u.sp.col[w][lane]      = P.featT[(size_t)p * C_IN + lane];
                u.sp.col[w][lane + 64] = P.featT[(size_t)p * C_IN + lane + 64];
            } else {
                u.sp.col[w][lane]      = P.feat[(size_t)lane * N_TOTAL + p];
                u.sp.col[w][lane + 64] = P.feat[(size_t)(lane + 64) * N_TOTAL + p];
            }
            // col is per-wave: intra-wave LDS ordering, no block sync needed
            float acc = bv[lane];
#pragma unroll 8
            for (int k = 0; k < C_IN; ++k)
                acc += u.sp.col[w][k] * u.sp.wt[k * 65 + lane];
            xout[(size_t)j * C_H + lane] = acc;
        }
    };

    // ---- one DGCN layer: 8 nodes/block, Ws/Wn staged in LDS ----
    auto dgcn = [&](const float* xin, const int* nbp,
                    const float* Wsl, const float* Wnl, const float* bias, int l,
                    float* xout, bool last, const float* head, const float* hb,
                    float* sdst, float* odst) {
        __syncthreads();                       // union handoff
        const float* Ws_ = Wsl + l * C_H * C_H;
        const float* Wn_ = Wnl + l * C_H * C_H;
        for (int i = tid; i < C_H * C_H; i += BLOCK) {
            u.dg.ws[i] = Ws_[i];               // [k][c] layout: reads conflict-free
            u.dg.wn[i] = Wn_[i];
        }
        __syncthreads();
        for (int ni = w; ni < 8; ni += 4) {
            int j = blk * 8 + ni;
            u.dg.xw[w][lane] = xin[(size_t)j * C_H + lane];
            float a = 0.f;
#pragma unroll
            for (int t = 0; t < KNB; ++t) {
                int q = nbp[j * KNB + t];
                a += xin[(size_t)q * C_H + lane];
            }
            u.dg.aw[w][lane] = a * (1.0f / KNB);
            // per-wave slots: intra-wave ordering only
            float acc = bias[l * C_H + lane];
#pragma unroll 8
            for (int k = 0; k < C_H; ++k)
                acc += u.dg.xw[w][k] * u.dg.ws[k * C_H + lane]
                     + u.dg.aw[w][k] * u.dg.wn[k * C_H + lane];
            acc = fmaxf(acc, 0.f);
            if (!last) {
                xout[(size_t)j * C_H + lane] = acc;
            } else {
                float v = acc * head[lane];
#pragma unroll
                for (int off = 32; off > 0; off >>= 1) v += __shfl_down(v, off, 64);
                if (lane == 0) {
                    float s = v + hb[0];
                    sdst[j] = s;
                    odst[j] = 1.f / (1.f + expf(-s));
                }
            }
        }
    };

    // ---- fused gather + per-row stable top-8; 8 rows/block (blocks 0..383) ----
    auto topk = [&](const int* isc) {
        __syncthreads();                       // union handoff
        const int b = (blk * 8) >> 10;         // branch, constant per block
        const int a = P.anchor[b];
        const int* row = isc + (size_t)a * N1;
        for (int m = tid; m < N1; m += BLOCK) {
            int pp = row[m];
            u.tk.sx[m] = P.xyz[pp * 3 + 0];
            u.tk.sy[m] = P.xyz[pp * 3 + 1];
            u.tk.sz[m] = P.xyz[pp * 3 + 2];
        }
        if (tid < 8) {
            int grow = blk * 8 + tid;
            P.indb[grow] = row[grow & (N1 - 1)];
        }
        __syncthreads();
#pragma unroll
        for (int rr = 0; rr < 2; ++rr) {
            const int grow = blk * 8 + rr * 4 + w;
            const int r = grow & (N1 - 1);
            float rx = u.tk.sx[r], ry = u.tk.sy[r], rz = u.tk.sz[r];
            unsigned long long k[16];
#pragma unroll
            for (int t = 0; t < 16; ++t) {
                int m = t * 64 + lane;         // lane-consecutive: conflict-free
                float v = fabsf(rx * u.tk.sx[m] + ry * u.tk.sy[m] + rz * u.tk.sz[m]);
                k[t] = ((unsigned long long)__float_as_uint(v) << 32)
                     | (unsigned int)(0xFFFFFFFFu - (unsigned int)m);
            }
#pragma unroll
            for (int pass = 0; pass < KNB; ++pass) {
                unsigned long long lm = k[0];
#pragma unroll
                for (int t = 1; t < 16; ++t) lm = (k[t] > lm) ? k[t] : lm;
#pragma unroll
                for (int off = 1; off < 64; off <<= 1) {
                    unsigned long long o = __shfl_xor(lm, off, 64);
                    lm = (o > lm) ? o : lm;
                }
                if (lane == 0) {
                    int idx = (int)(0xFFFFFFFFu - (unsigned int)(lm & 0xFFFFFFFFull));
                    P.nbb[grow * KNB + pass] = b * N1 + idx;
                }
#pragma unroll
                for (int t = 0; t < 16; ++t) if (k[t] == lm) k[t] = 0;
            }
        }
        __syncthreads();
    };

    unsigned tA = 0;
    auto SYNCA = [&]() { tA += GRID; gbar(P.cntA, tA); };

    // ===== P_tr: feat transpose (32 columns/block) + xyz0 gather =====
    if (P.tr) {
        float (*t)[129] = (float (*)[129])u.sp.wt;   // 16.5KB tile, aliases union
        const int colL = tid & 31, rowH = tid >> 5;  // 32 cols x 8 rows per pass
        const int g32 = blk * 32;
        for (int c0 = 0; c0 < C_IN; c0 += 8) {
            int c = c0 + rowH;
            t[colL][c] = P.feat[(size_t)c * N_TOTAL + g32 + colL];
        }
        __syncthreads();
        for (int i = tid; i < 32 * C_IN; i += BLOCK) {
            int col = i >> 7, c = i & 127;
            P.featT[(size_t)(g32 + col) * C_IN + c] = t[col][c];
        }
    }
    if (tid < 8) {
        int j = blk * 8 + tid;
        int p = P.ind0[j];
        P.xyz0[j * 3 + 0] = P.xyz[p * 3 + 0];
        P.xyz0[j * 3 + 1] = P.xyz[p * 3 + 1];
        P.xyz0[j * 3 + 2] = P.xyz[p * 3 + 2];
    }
    SYNCA();   // B1

    // ===== stage 0 =====
    sphere(P.ind0, P.wsS[0], P.bsS[0], P.xA);
    SYNCA();   // B2
    dgcn(P.xA, P.nb0, P.dgWs[0], P.dgWn[0], P.dgB[0], 0, P.xB, false, nullptr, nullptr, nullptr, nullptr);
    SYNCA();   // B3
    dgcn(P.xB, P.nb0, P.dgWs[0], P.dgWn[0], P.dgB[0], 1, P.xA, false, nullptr, nullptr, nullptr, nullptr);
    SYNCA();   // B4
    dgcn(P.xA, P.nb0, P.dgWs[0], P.dgWn[0], P.dgB[0], 2, P.xB, false, nullptr, nullptr, nullptr, nullptr);
    SYNCA();   // B5
    dgcn(P.xB, P.nb0, P.dgWs[0], P.dgWn[0], P.dgB[0], 3, nullptr, true,
         P.dgH[0], P.dgHb[0], P.s0, P.out);

    // ===== B6: blocks >= NACT arrive and exit; actives wait for all 1024 =====
    if (blk >= NACT) {
        __syncthreads();
        if (tid == 0) {
            __builtin_amdgcn_fence(__ATOMIC_RELEASE, "agent");
            __hip_atomic_fetch_add(P.cntA, 1u, __ATOMIC_RELAXED, __HIP_MEMORY_SCOPE_AGENT);
        }
        return;
    }
    SYNCA();   // B6 (target 6*GRID: exact, every block adds exactly 1 to cntA)

    // ===== NMS (block 0; scores in LDS; xyz0 pre-gathered) =====
    if (blk == 0) {
        for (int jj = tid; jj < N0; jj += BLOCK) u.sc[jj] = P.s0[jj];
        __syncthreads();
        for (int it = 0; it < 3; ++it) {
            float bv = -INFINITY; int bi = 0x7fffffff;
            for (int jj = tid; jj < N0; jj += BLOCK) {
                float v = u.sc[jj];
                if (v > bv) { bv = v; bi = jj; }   // strided ascending: first max kept
            }
            rv[tid] = bv; ri[tid] = bi;
            __syncthreads();
            for (int sft = BLOCK / 2; sft > 0; sft >>= 1) {
                if (tid < sft) {
                    float v2 = rv[tid + sft]; int i2 = ri[tid + sft];
                    if (v2 > rv[tid] || (v2 == rv[tid] && i2 < ri[tid])) {
                        rv[tid] = v2; ri[tid] = i2;
                    }
                }
                __syncthreads();
            }
            int sel = ri[0];
            if (tid == 0) {
                P.anchor[it] = P.ind0[sel];
                psel[0] = P.xyz0[sel * 3 + 0];
                psel[1] = P.xyz0[sel * 3 + 1];
                psel[2] = P.xyz0[sel * 3 + 2];
            }
            __syncthreads();
            float px = psel[0], py = psel[1], pz = psel[2];
            for (int jj = tid; jj < N0; jj += BLOCK) {
                float d = fabsf(P.xyz0[jj * 3 + 0] * px + P.xyz0[jj * 3 + 1] * py
                              + P.xyz0[jj * 3 + 2] * pz);
                if (d >= COS_T) u.sc[jj] = NEG_INF;
            }
            __syncthreads();
        }
    }

    unsigned tB = 0;
    auto SYNCB = [&]() { tB += NACT; gbar(P.cntB, tB); };
    SYNCB();   // B7

    // ===== stages 1 & 2 (384 blocks) =====
    for (int st = 1; st <= 2; ++st) {
        topk(P.isc[st - 1]);
        sphere(P.indb, P.wsS[st], P.bsS[st], P.xA);   // same 8 nodes as topk rows
        SYNCB();   // B8 / B14
        dgcn(P.xA, P.nbb, P.dgWs[st], P.dgWn[st], P.dgB[st], 0, P.xB, false, nullptr, nullptr, nullptr, nullptr);
        SYNCB();   // B9 / B15
        dgcn(P.xB, P.nbb, P.dgWs[st], P.dgWn[st], P.dgB[st], 1, P.xA, false, nullptr, nullptr, nullptr, nullptr);
        SYNCB();   // B10 / B16
        dgcn(P.xA, P.nbb, P.dgWs[st], P.dgWn[st], P.dgB[st], 2, P.xB, false, nullptr, nullptr, nullptr, nullptr);
        SYNCB();   // B11 / B17
        dgcn(P.xB, P.nbb, P.dgWs[st], P.dgWn[st], P.dgB[st], 3, nullptr, true,
             P.dgH[st], P.dgHb[st], P.sbr, P.out + N0 + (st - 1) * 3 * N1);
        if (st == 1) {
            SYNCB();   // B12
            if (blk < 3) {
                float bv = -INFINITY; int bi = 0x7fffffff;
                for (int m = tid; m < N1; m += BLOCK) {
                    float v = P.sbr[blk * N1 + m];
                    if (v > bv) { bv = v; bi = m; }
                }
                rv[tid] = bv; ri[tid] = bi;
                __syncthreads();
                for (int sft = BLOCK / 2; sft > 0; sft >>= 1) {
                    if (tid < sft) {
                        float v2 = rv[tid + sft]; int i2 = ri[tid + sft];
                        if (v2 > rv[tid] || (v2 == rv[tid] && i2 < ri[tid])) {
                            rv[tid] = v2; ri[tid] = i2;
                        }
                    }
                    __syncthreads();
                }
                if (tid == 0) P.anchor[blk] = P.indb[blk * N1 + ri[0]];
            }
            SYNCB();   // B13
        }
    }
}

extern "C" void kernel_launch(void* const* d_in, const int* in_sizes, int n_in,
                              void* d_out, int out_size, void* d_ws, size_t ws_size,
                              hipStream_t stream) {
    MegaParams hp;
    hp.feat = (const float*)d_in[0];
    hp.xyz  = (const float*)d_in[1];
    hp.wsS[0] = (const float*)d_in[2];  hp.bsS[0] = (const float*)d_in[3];
    hp.wsS[1] = (const float*)d_in[4];  hp.bsS[1] = (const float*)d_in[5];
    hp.wsS[2] = (const float*)d_in[6];  hp.bsS[2] = (const float*)d_in[7];
    hp.dgWs[0] = (const float*)d_in[8];  hp.dgWn[0] = (const float*)d_in[9];
    hp.dgB[0]  = (const float*)d_in[10]; hp.dgH[0]  = (const float*)d_in[11];
    hp.dgHb[0] = (const float*)d_in[12];
    hp.dgWs[1] = (const float*)d_in[13]; hp.dgWn[1] = (const float*)d_in[14];
    hp.dgB[1]  = (const float*)d_in[15]; hp.dgH[1]  = (const float*)d_in[16];
    hp.dgHb[1] = (const float*)d_in[17];
    hp.dgWs[2] = (const float*)d_in[18]; hp.dgWn[2] = (const float*)d_in[19];
    hp.dgB[2]  = (const float*)d_in[20]; hp.dgH[2]  = (const float*)d_in[21];
    hp.dgHb[2] = (const float*)d_in[22];
    const int* edge0 = (const int*)d_in[23];
    hp.nb0  = edge0 + N0 * KNB;
    hp.ind0 = (const int*)d_in[24];
    hp.isc[0] = (const int*)d_in[25];
    hp.isc[1] = (const int*)d_in[26];
    hp.out = (float*)d_out;

    // workspace layout (floats)
    float* f = (float*)d_ws;
    size_t o = 0;
    hp.xA   = f + o; o += (size_t)N0 * C_H;      // 524288
    hp.xB   = f + o; o += (size_t)N0 * C_H;      // 524288
    hp.s0   = f + o; o += N0;                    // 8192
    hp.sbr  = f + o; o += 3 * N1;                // 3072
    hp.xyz0 = f + o; o += (size_t)N0 * 3;        // 24576
    hp.anchor = (int*)(f + o); o += 4;
    hp.indb   = (int*)(f + o); o += 3 * N1;      // 3072
    hp.nbb    = (int*)(f + o); o += 3 * N1 * KNB; // 24576
    o = (o + 31) & ~(size_t)31;                  // 128B align
    hp.cntA = (unsigned*)(f + o);
    hp.cntB = hp.cntA + 16;                      // separate cacheline
    o += 32;
    hp.featT = f + o;
    size_t need = (o + (size_t)N_TOTAL * C_IN) * sizeof(float);
    hp.tr = (ws_size >= need) ? 1 : 0;

    hipMemsetAsync((void*)hp.cntA, 0, 128, stream);  // reset both counters
    mega_kernel<<<dim3(GRID), dim3(BLOCK), 0, stream>>>(hp);
}

// Round 4
// 368.564 us; speedup vs baseline: 8.6477x; 2.3237x over previous
//
#include <hip/hip_runtime.h>
#include <math.h>

#define N_TOTAL 32768
#define N0 8192
#define N1 1024
#define KNB 8
#define C_IN 128
#define C_H 64
#define COS_T 0.999f
#define NEG_INF -1e30f
#define GRID 256
#define BLOCK 1024
#define NACT 96       // blocks that stay alive after stage 0

// ---- agent-coherent (sc1) accessors: bypass non-coherent per-XCD L2,
// ---- coherent at the Infinity-Cache point. Used for ALL cross-block data.
__device__ __forceinline__ float ldc(const float* p) {
    return __hip_atomic_load((const float*)p, __ATOMIC_RELAXED, __HIP_MEMORY_SCOPE_AGENT);
}
__device__ __forceinline__ void stc(float* p, float v) {
    __hip_atomic_store(p, v, __ATOMIC_RELAXED, __HIP_MEMORY_SCOPE_AGENT);
}
__device__ __forceinline__ int ldci(const int* p) {
    return __hip_atomic_load((const int*)p, __ATOMIC_RELAXED, __HIP_MEMORY_SCOPE_AGENT);
}
__device__ __forceinline__ void stci(int* p, int v) {
    __hip_atomic_store(p, v, __ATOMIC_RELAXED, __HIP_MEMORY_SCOPE_AGENT);
}

struct MegaParams {
    const float* feat;
    const float* xyz;
    const float* wsS[3];
    const float* bsS[3];
    const float* dgWs[3];
    const float* dgWn[3];
    const float* dgB[3];
    const float* dgH[3];
    const float* dgHb[3];
    const int* nb0;
    const int* ind0;
    const int* isc[2];
    float* out;
    float* xA;
    float* xB;
    float* s0;
    float* sbr;
    float* xyz0;
    float* featT;
    int* anchor;
    int* indb;
    int* nbb;
    unsigned* cntA;
    unsigned* cntB;
    int tr;
};

// Fence-free grid barrier: per-wave vmcnt drain (sc1 stores reach the
// coherence point) -> block sync -> relaxed agent add+poll. NO buffer_wbl2 /
// buffer_inv — caches stay warm; cross-block data is sc1 so needs no fences.
// Valid: all 256 blocks co-resident (1/CU; LDS 49.7KB, VGPR<=128).
__device__ __forceinline__ void gbar(unsigned* c, unsigned target) {
    asm volatile("s_waitcnt vmcnt(0)" ::: "memory");
    __syncthreads();
    if (threadIdx.x == 0) {
        __hip_atomic_fetch_add(c, 1u, __ATOMIC_RELAXED, __HIP_MEMORY_SCOPE_AGENT);
        while (__hip_atomic_load(c, __ATOMIC_RELAXED, __HIP_MEMORY_SCOPE_AGENT) < target)
            __builtin_amdgcn_s_sleep(2);
    }
    __syncthreads();
}
// block-local publish: my sc1 writes visible to my own later readers
__device__ __forceinline__ void bsync() {
    asm volatile("s_waitcnt vmcnt(0)" ::: "memory");
    __syncthreads();
}

__global__ void __launch_bounds__(BLOCK) mega_kernel(MegaParams P) {
    const int blk = blockIdx.x;
    const int tid = threadIdx.x;
    const int w = tid >> 6;      // wave id 0..15
    const int lane = tid & 63;   // channel

    __shared__ union {
        float tt[64][129];                                        // 33.0KB (transpose)
        struct { float wt[C_IN * 65]; float col[16][C_IN]; } sp;  // 41.5KB (sphere)
        struct { float ws[C_H * C_H]; float wn[C_H * C_H];
                 float xw[16][C_H]; float aw[16][C_H]; } dg;      // 40KB   (dgcn)
        struct { float sx[N1]; float sy[N1]; float sz[N1]; } tk;  // 12KB   (topk)
        float sc[N0];                                             // 32KB   (NMS)
    } u;
    __shared__ float rv[BLOCK];
    __shared__ int ri[BLOCK];
    __shared__ float psel[3];

    // ---- sphere: 32 nodes/block, W^T staged in LDS ----
    auto sphere = [&](const int* ind, bool indCoh, const float* W, const float* bv,
                      float* xout) {
        __syncthreads();                          // union handoff
        for (int i = tid; i < C_H * C_IN; i += BLOCK) {
            int c = i >> 7, k = i & 127;
            u.sp.wt[k * 65 + c] = W[i];           // normal cached load (read-only input)
        }
        __syncthreads();
#pragma unroll
        for (int it = 0; it < 2; ++it) {
            int j = blk * 32 + it * 16 + w;
            int p = indCoh ? ldci(&ind[j]) : ind[j];
            if (P.tr) {
                u.sp.col[w][lane]      = ldc(&P.featT[(size_t)p * C_IN + lane]);
                u.sp.col[w][lane + 64] = ldc(&P.featT[(size_t)p * C_IN + lane + 64]);
            } else {
                u.sp.col[w][lane]      = P.feat[(size_t)lane * N_TOTAL + p];
                u.sp.col[w][lane + 64] = P.feat[(size_t)(lane + 64) * N_TOTAL + p];
            }
            float acc = bv[lane];
#pragma unroll 8
            for (int k = 0; k < C_IN; ++k)
                acc += u.sp.col[w][k] * u.sp.wt[k * 65 + lane];
            stc(&xout[(size_t)j * C_H + lane], acc);
        }
    };

    // ---- one DGCN layer: 32 nodes/block, Ws/Wn staged in LDS ----
    auto dgcn = [&](const float* xin, const int* nbp, bool nbCoh,
                    const float* Wsl, const float* Wnl, const float* bias, int l,
                    float* xout, bool last, const float* head, const float* hb,
                    float* sdst, float* odst) {
        __syncthreads();                          // union handoff
        const float* Ws_ = Wsl + l * C_H * C_H;
        const float* Wn_ = Wnl + l * C_H * C_H;
        for (int i = tid; i < C_H * C_H; i += BLOCK) {
            u.dg.ws[i] = Ws_[i];
            u.dg.wn[i] = Wn_[i];
        }
        __syncthreads();
        for (int ni = w; ni < 32; ni += 16) {
            int j = blk * 32 + ni;
            u.dg.xw[w][lane] = ldc(&xin[(size_t)j * C_H + lane]);
            float a = 0.f;
#pragma unroll
            for (int t = 0; t < KNB; ++t) {
                int q = nbCoh ? ldci(&nbp[j * KNB + t]) : nbp[j * KNB + t];
                a += ldc(&xin[(size_t)q * C_H + lane]);
            }
            u.dg.aw[w][lane] = a * (1.0f / KNB);
            // per-wave LDS slots: intra-wave ordering only
            float acc = bias[l * C_H + lane];
#pragma unroll 8
            for (int k = 0; k < C_H; ++k)
                acc += u.dg.xw[w][k] * u.dg.ws[k * C_H + lane]
                     + u.dg.aw[w][k] * u.dg.wn[k * C_H + lane];
            acc = fmaxf(acc, 0.f);
            if (!last) {
                stc(&xout[(size_t)j * C_H + lane], acc);
            } else {
                float v = acc * head[lane];
#pragma unroll
                for (int off = 32; off > 0; off >>= 1) v += __shfl_down(v, off, 64);
                if (lane == 0) {
                    float s = v + hb[0];
                    stc(&sdst[j], s);
                    stc(&odst[j], 1.f / (1.f + expf(-s)));
                }
            }
        }
    };

    // ---- fused gather + per-row stable top-8; 32 rows/block (blocks 0..95) ----
    auto topk = [&](const int* isc) {
        __syncthreads();                          // union handoff
        const int b = blk >> 5;                   // branch (32 blocks per branch)
        const int a = ldci(&P.anchor[b]);
        const int* row = isc + (size_t)a * N1;    // read-only input: normal loads
        {
            int pp = row[tid & (N1 - 1)];         // tid<1024 == N1: one element each
            u.tk.sx[tid] = P.xyz[pp * 3 + 0];
            u.tk.sy[tid] = P.xyz[pp * 3 + 1];
            u.tk.sz[tid] = P.xyz[pp * 3 + 2];
        }
        if (tid < 32) {
            int grow = blk * 32 + tid;
            stci(&P.indb[grow], row[grow & (N1 - 1)]);
        }
        __syncthreads();
#pragma unroll
        for (int rr = 0; rr < 2; ++rr) {
            const int grow = blk * 32 + rr * 16 + w;
            const int r = grow & (N1 - 1);
            float rx = u.tk.sx[r], ry = u.tk.sy[r], rz = u.tk.sz[r];
            unsigned long long k[16];
#pragma unroll
            for (int t = 0; t < 16; ++t) {
                int m = t * 64 + lane;            // lane-consecutive: conflict-free
                float v = fabsf(rx * u.tk.sx[m] + ry * u.tk.sy[m] + rz * u.tk.sz[m]);
                k[t] = ((unsigned long long)__float_as_uint(v) << 32)
                     | (unsigned int)(0xFFFFFFFFu - (unsigned int)m);
            }
#pragma unroll
            for (int pass = 0; pass < KNB; ++pass) {
                unsigned long long lm = k[0];
#pragma unroll
                for (int t = 1; t < 16; ++t) lm = (k[t] > lm) ? k[t] : lm;
#pragma unroll
                for (int off = 1; off < 64; off <<= 1) {
                    unsigned long long o = __shfl_xor(lm, off, 64);
                    lm = (o > lm) ? o : lm;
                }
                if (lane == 0) {
                    int idx = (int)(0xFFFFFFFFu - (unsigned int)(lm & 0xFFFFFFFFull));
                    stci(&P.nbb[grow * KNB + pass], b * N1 + idx);
                }
#pragma unroll
                for (int t = 0; t < 16; ++t) if (k[t] == lm) k[t] = 0;
            }
        }
        bsync();   // publish indb/nbb for this block's own sphere/dgcn reads
    };

    unsigned tA = 0;
    auto SYNCA = [&]() { tA += GRID; gbar(P.cntA, tA); };

    // ===== featT transpose (128 cols/block, two 64-col passes) + xyz0 gather =====
    if (P.tr) {
#pragma unroll
        for (int ps = 0; ps < 2; ++ps) {
            const int g0 = blk * 128 + ps * 64;
            __syncthreads();
            for (int c0 = 0; c0 < C_IN; c0 += 16) {
                int c = c0 + (tid >> 6);
                int col = tid & 63;
                u.tt[col][c] = P.feat[(size_t)c * N_TOTAL + g0 + col];  // coalesced
            }
            __syncthreads();
            for (int i = tid; i < 64 * C_IN; i += BLOCK) {
                int col = i >> 7, c = i & 127;
                stc(&P.featT[(size_t)(g0 + col) * C_IN + c], u.tt[col][c]);  // coalesced
            }
        }
    }
    if (tid < 32) {
        int j = blk * 32 + tid;
        int p = P.ind0[j];
        stc(&P.xyz0[j * 3 + 0], P.xyz[p * 3 + 0]);
        stc(&P.xyz0[j * 3 + 1], P.xyz[p * 3 + 1]);
        stc(&P.xyz0[j * 3 + 2], P.xyz[p * 3 + 2]);
    }
    SYNCA();   // B1

    // ===== stage 0 =====
    sphere(P.ind0, false, P.wsS[0], P.bsS[0], P.xA);
    SYNCA();   // B2
    dgcn(P.xA, P.nb0, false, P.dgWs[0], P.dgWn[0], P.dgB[0], 0, P.xB, false, nullptr, nullptr, nullptr, nullptr);
    SYNCA();   // B3
    dgcn(P.xB, P.nb0, false, P.dgWs[0], P.dgWn[0], P.dgB[0], 1, P.xA, false, nullptr, nullptr, nullptr, nullptr);
    SYNCA();   // B4
    dgcn(P.xA, P.nb0, false, P.dgWs[0], P.dgWn[0], P.dgB[0], 2, P.xB, false, nullptr, nullptr, nullptr, nullptr);
    SYNCA();   // B5
    dgcn(P.xB, P.nb0, false, P.dgWs[0], P.dgWn[0], P.dgB[0], 3, nullptr, true,
         P.dgH[0], P.dgHb[0], P.s0, P.out);

    // ===== B6: blocks >= NACT arrive and exit =====
    if (blk >= NACT) {
        asm volatile("s_waitcnt vmcnt(0)" ::: "memory");
        __syncthreads();
        if (tid == 0)
            __hip_atomic_fetch_add(P.cntA, 1u, __ATOMIC_RELAXED, __HIP_MEMORY_SCOPE_AGENT);
        return;
    }
    SYNCA();   // B6 (target 6*GRID: every block adds exactly 6 total)

    // ===== NMS (block 0; scores + xyz0 via sc1; work in LDS) =====
    if (blk == 0) {
        for (int jj = tid; jj < N0; jj += BLOCK) u.sc[jj] = ldc(&P.s0[jj]);
        __syncthreads();
        for (int it = 0; it < 3; ++it) {
            float bv = -INFINITY; int bi = 0x7fffffff;
            for (int jj = tid; jj < N0; jj += BLOCK) {
                float v = u.sc[jj];
                if (v > bv) { bv = v; bi = jj; }   // strided ascending: first max kept
            }
            rv[tid] = bv; ri[tid] = bi;
            __syncthreads();
            for (int sft = BLOCK / 2; sft > 0; sft >>= 1) {
                if (tid < sft) {
                    float v2 = rv[tid + sft]; int i2 = ri[tid + sft];
                    if (v2 > rv[tid] || (v2 == rv[tid] && i2 < ri[tid])) {
                        rv[tid] = v2; ri[tid] = i2;
                    }
                }
                __syncthreads();
            }
            int sel = ri[0];
            if (tid == 0) {
                stci(&P.anchor[it], P.ind0[sel]);
                psel[0] = ldc(&P.xyz0[sel * 3 + 0]);
                psel[1] = ldc(&P.xyz0[sel * 3 + 1]);
                psel[2] = ldc(&P.xyz0[sel * 3 + 2]);
            }
            __syncthreads();
            float px = psel[0], py = psel[1], pz = psel[2];
            for (int jj = tid; jj < N0; jj += BLOCK) {
                float d = fabsf(ldc(&P.xyz0[jj * 3 + 0]) * px
                              + ldc(&P.xyz0[jj * 3 + 1]) * py
                              + ldc(&P.xyz0[jj * 3 + 2]) * pz);
                if (d >= COS_T) u.sc[jj] = NEG_INF;
            }
            __syncthreads();
        }
    }

    unsigned tB = 0;
    auto SYNCB = [&]() { tB += NACT; gbar(P.cntB, tB); };
    SYNCB();   // B7

    // ===== stages 1 & 2 (96 blocks x 32 rows) =====
    for (int st = 1; st <= 2; ++st) {
        topk(P.isc[st - 1]);
        sphere(P.indb, true, P.wsS[st], P.bsS[st], P.xA);   // same 32 rows as topk
        SYNCB();   // B8 / B14
        dgcn(P.xA, P.nbb, true, P.dgWs[st], P.dgWn[st], P.dgB[st], 0, P.xB, false, nullptr, nullptr, nullptr, nullptr);
        SYNCB();   // B9 / B15
        dgcn(P.xB, P.nbb, true, P.dgWs[st], P.dgWn[st], P.dgB[st], 1, P.xA, false, nullptr, nullptr, nullptr, nullptr);
        SYNCB();   // B10 / B16
        dgcn(P.xA, P.nbb, true, P.dgWs[st], P.dgWn[st], P.dgB[st], 2, P.xB, false, nullptr, nullptr, nullptr, nullptr);
        SYNCB();   // B11 / B17
        dgcn(P.xB, P.nbb, true, P.dgWs[st], P.dgWn[st], P.dgB[st], 3, nullptr, true,
             P.dgH[st], P.dgHb[st], P.sbr, P.out + N0 + (st - 1) * 3 * N1);
        if (st == 1) {
            SYNCB();   // B12
            if (blk < 3) {
                float bv = -INFINITY; int bi = 0x7fffffff;
                {
                    float v = ldc(&P.sbr[blk * N1 + tid]);   // tid<1024==N1
                    bv = v; bi = tid;
                }
                rv[tid] = bv; ri[tid] = bi;
                __syncthreads();
                for (int sft = BLOCK / 2; sft > 0; sft >>= 1) {
                    if (tid < sft) {
                        float v2 = rv[tid + sft]; int i2 = ri[tid + sft];
                        if (v2 > rv[tid] || (v2 == rv[tid] && i2 < ri[tid])) {
                            rv[tid] = v2; ri[tid] = i2;
                        }
                    }
                    __syncthreads();
                }
                if (tid == 0) stci(&P.anchor[blk], ldci(&P.indb[blk * N1 + ri[0]]));
            }
            SYNCB();   // B13
        }
    }
}

extern "C" void kernel_launch(void* const* d_in, const int* in_sizes, int n_in,
                              void* d_out, int out_size, void* d_ws, size_t ws_size,
                              hipStream_t stream) {
    MegaParams hp;
    hp.feat = (const float*)d_in[0];
    hp.xyz  = (const float*)d_in[1];
    hp.wsS[0] = (const float*)d_in[2];  hp.bsS[0] = (const float*)d_in[3];
    hp.wsS[1] = (const float*)d_in[4];  hp.bsS[1] = (const float*)d_in[5];
    hp.wsS[2] = (const float*)d_in[6];  hp.bsS[2] = (const float*)d_in[7];
    hp.dgWs[0] = (const float*)d_in[8];  hp.dgWn[0] = (const float*)d_in[9];
    hp.dgB[0]  = (const float*)d_in[10]; hp.dgH[0]  = (const float*)d_in[11];
    hp.dgHb[0] = (const float*)d_in[12];
    hp.dgWs[1] = (const float*)d_in[13]; hp.dgWn[1] = (const float*)d_in[14];
    hp.dgB[1]  = (const float*)d_in[15]; hp.dgH[1]  = (const float*)d_in[16];
    hp.dgHb[1] = (const float*)d_in[17];
    hp.dgWs[2] = (const float*)d_in[18]; hp.dgWn[2] = (const float*)d_in[19];
    hp.dgB[2]  = (const float*)d_in[20]; hp.dgH[2]  = (const float*)d_in[21];
    hp.dgHb[2] = (const float*)d_in[22];
    const int* edge0 = (const int*)d_in[23];
    hp.nb0  = edge0 + N0 * KNB;
    hp.ind0 = (const int*)d_in[24];
    hp.isc[0] = (const int*)d_in[25];
    hp.isc[1] = (const int*)d_in[26];
    hp.out = (float*)d_out;

    // workspace layout (floats)
    float* f = (float*)d_ws;
    size_t o = 0;
    hp.xA   = f + o; o += (size_t)N0 * C_H;
    hp.xB   = f + o; o += (size_t)N0 * C_H;
    hp.s0   = f + o; o += N0;
    hp.sbr  = f + o; o += 3 * N1;
    hp.xyz0 = f + o; o += (size_t)N0 * 3;
    hp.anchor = (int*)(f + o); o += 4;
    hp.indb   = (int*)(f + o); o += 3 * N1;
    hp.nbb    = (int*)(f + o); o += 3 * N1 * KNB;
    o = (o + 31) & ~(size_t)31;
    hp.cntA = (unsigned*)(f + o);
    hp.cntB = hp.cntA + 16;
    o += 32;
    hp.featT = f + o;
    size_t need = (o + (size_t)N_TOTAL * C_IN) * sizeof(float);
    hp.tr = (ws_size >= need) ? 1 : 0;

    hipMemsetAsync((void*)hp.cntA, 0, 128, stream);
    mega_kernel<<<dim3(GRID), dim3(BLOCK), 0, stream>>>(hp);
}

// Round 5
// 292.500 us; speedup vs baseline: 10.8966x; 1.2601x over previous
//
#include <hip/hip_runtime.h>
#include <math.h>

#define N_TOTAL 32768
#define N0 8192
#define N1 1024
#define KNB 8
#define C_IN 128
#define C_H 64
#define COS_T 0.999f
#define NEG_INF -1e30f
#define GRID 256
#define BLOCK 1024
#define NACT 96       // blocks that stay alive after stage 0

// ---- sc1 agent-scope accessors: write-through to the Infinity-Cache
// ---- coherence point. Producers of cross-block data STORE with these;
// ---- consumers use PLAIN cached loads (valid because each buffer is
// ---- written before any read of it in this launch — distinct buffers,
// ---- and dispatch start invalidates L2, proven by the multi-kernel
// ---- baseline's correctness with plain ping-ponged buffers).
__device__ __forceinline__ float ldc(const float* p) {
    return __hip_atomic_load(p, __ATOMIC_RELAXED, __HIP_MEMORY_SCOPE_AGENT);
}
__device__ __forceinline__ void stc(float* p, float v) {
    __hip_atomic_store(p, v, __ATOMIC_RELAXED, __HIP_MEMORY_SCOPE_AGENT);
}
__device__ __forceinline__ void stci(int* p, int v) {
    __hip_atomic_store(p, v, __ATOMIC_RELAXED, __HIP_MEMORY_SCOPE_AGENT);
}

struct MegaParams {
    const float* feat;
    const float* xyz;
    const float* wsS[3];
    const float* bsS[3];
    const float* dgWs[3];
    const float* dgWn[3];
    const float* dgB[3];
    const float* dgH[3];
    const float* dgHb[3];
    const int* nb0;
    const int* ind0;
    const int* isc[2];
    float* out;
    float* xs0[4];    // stage0: sphere-out, l0-out, l1-out, l2-out
    float* xs1[4];    // stage1
    float* xs2[4];    // stage2
    float* s0;
    float* sbr;
    float* xyz0;
    int* anchorA;     // NMS result      (own 256B line)
    int* anchorB;     // argmax result   (own 256B line)
    int* indb1; int* nbb1;
    int* indb2; int* nbb2;
    unsigned* cnt;    // arrival counter (own 256B line)
    unsigned* flag;   // epoch broadcast (own 256B line)
    int actCoh;       // 1 = small-ws fallback: activations read via sc1
};

__global__ void __launch_bounds__(BLOCK) mega_kernel(MegaParams P) {
    const int blk = blockIdx.x;
    const int tid = threadIdx.x;
    const int w = tid >> 6;      // wave id 0..15
    const int lane = tid & 63;   // channel

    __shared__ union {
        struct { float wt[C_IN * 65]; float col[16][C_IN]; } sp;  // 41.5KB (sphere)
        struct { float ws[C_H * C_H]; float wn[C_H * C_H];
                 float xw[16][C_H]; float aw[16][C_H]; } dg;      // 40KB   (dgcn)
        struct { float sx[N1]; float sy[N1]; float sz[N1]; } tk;  // 12KB   (topk)
        float sc[N0];                                             // 32KB   (NMS)
    } u;
    __shared__ float rv[BLOCK];
    __shared__ int ri[BLOCK];
    __shared__ float psel[3];

    // Grid barrier: drain sc1 stores -> arrive (1 RMW/block) -> block 0 polls
    // the counter and broadcasts epoch via flag; others poll the read-only
    // flag line. No cache-wide fences anywhere: caches stay warm.
    auto BAR = [&](int e) {
        asm volatile("s_waitcnt vmcnt(0)" ::: "memory");
        __syncthreads();
        if (tid == 0) {
            __hip_atomic_fetch_add(P.cnt, 1u, __ATOMIC_RELAXED, __HIP_MEMORY_SCOPE_AGENT);
            if (blk == 0) {
                unsigned tgt = (e <= 6) ? (unsigned)(GRID * e)
                                        : (unsigned)(GRID * 6 + NACT * (e - 6));
                while (__hip_atomic_load(P.cnt, __ATOMIC_RELAXED, __HIP_MEMORY_SCOPE_AGENT) < tgt)
                    __builtin_amdgcn_s_sleep(2);
                __hip_atomic_store(P.flag, (unsigned)e, __ATOMIC_RELAXED, __HIP_MEMORY_SCOPE_AGENT);
            } else {
                while (__hip_atomic_load(P.flag, __ATOMIC_RELAXED, __HIP_MEMORY_SCOPE_AGENT) < (unsigned)e)
                    __builtin_amdgcn_s_sleep(4);
            }
        }
        __syncthreads();
    };

    // ---- sphere: 32 nodes/block, W^T staged in LDS; scattered feat gather
    // ---- is plain cached (read-only input, L2/L3 reuse) ----
    auto sphere = [&](const int* ind, const float* W, const float* bv, float* xout) {
        __syncthreads();                          // union handoff
        for (int i = tid; i < C_H * C_IN; i += BLOCK) {
            int c = i >> 7, k = i & 127;
            u.sp.wt[k * 65 + c] = W[i];
        }
        __syncthreads();
#pragma unroll
        for (int it = 0; it < 2; ++it) {
            int j = blk * 32 + it * 16 + w;
            int p = ind[j];
            u.sp.col[w][lane]      = P.feat[(size_t)lane * N_TOTAL + p];
            u.sp.col[w][lane + 64] = P.feat[(size_t)(lane + 64) * N_TOTAL + p];
            float acc = bv[lane];
#pragma unroll 8
            for (int k = 0; k < C_IN; ++k)
                acc += u.sp.col[w][k] * u.sp.wt[k * 65 + lane];
            stc(&xout[(size_t)j * C_H + lane], acc);
        }
    };

    // ---- one DGCN layer: 32 nodes/block; activations plain-cached (fast)
    // ---- or sc1 (fallback); weights staged in LDS ----
    auto dgcn = [&](const float* xin, const int* nbp,
                    const float* Wsl, const float* Wnl, const float* bias, int l,
                    float* xout, bool last, const float* head, const float* hb,
                    float* sdst, float* odst) {
        __syncthreads();                          // union handoff
        const float* Ws_ = Wsl + l * C_H * C_H;
        const float* Wn_ = Wnl + l * C_H * C_H;
        for (int i = tid; i < C_H * C_H; i += BLOCK) {
            u.dg.ws[i] = Ws_[i];
            u.dg.wn[i] = Wn_[i];
        }
        __syncthreads();
        for (int ni = w; ni < 32; ni += 16) {
            int j = blk * 32 + ni;
            float xv, a = 0.f;
            if (!P.actCoh) {
                xv = xin[(size_t)j * C_H + lane];
#pragma unroll
                for (int t = 0; t < KNB; ++t) {
                    int q = nbp[j * KNB + t];
                    a += xin[(size_t)q * C_H + lane];
                }
            } else {
                xv = ldc(&xin[(size_t)j * C_H + lane]);
#pragma unroll
                for (int t = 0; t < KNB; ++t) {
                    int q = nbp[j * KNB + t];
                    a += ldc(&xin[(size_t)q * C_H + lane]);
                }
            }
            u.dg.xw[w][lane] = xv;
            u.dg.aw[w][lane] = a * (1.0f / KNB);
            float acc = bias[l * C_H + lane];
#pragma unroll 8
            for (int k = 0; k < C_H; ++k)
                acc += u.dg.xw[w][k] * u.dg.ws[k * C_H + lane]
                     + u.dg.aw[w][k] * u.dg.wn[k * C_H + lane];
            acc = fmaxf(acc, 0.f);
            if (!last) {
                stc(&xout[(size_t)j * C_H + lane], acc);
            } else {
                float v = acc * head[lane];
#pragma unroll
                for (int off = 32; off > 0; off >>= 1) v += __shfl_down(v, off, 64);
                if (lane == 0) {
                    float s = v + hb[0];
                    if (sdst) stc(&sdst[j], s);
                    odst[j] = 1.f / (1.f + expf(-s));   // out: plain (flushed at kernel end)
                }
            }
        }
    };

    // ---- fused gather + per-row stable top-8; 32 rows/block ----
    auto topk = [&](const int* isc, const int* anc, int* indb, int* nbb) {
        __syncthreads();                          // union handoff
        const int b = blk >> 5;                   // branch (32 blocks per branch)
        const int a = anc[b];                     // plain (fresh line)
        const int* row = isc + (size_t)a * N1;
        {
            int pp = row[tid & (N1 - 1)];
            u.tk.sx[tid] = P.xyz[pp * 3 + 0];
            u.tk.sy[tid] = P.xyz[pp * 3 + 1];
            u.tk.sz[tid] = P.xyz[pp * 3 + 2];
        }
        if (tid < 32) {
            int grow = blk * 32 + tid;
            stci(&indb[grow], row[grow & (N1 - 1)]);
        }
        __syncthreads();
#pragma unroll
        for (int rr = 0; rr < 2; ++rr) {
            const int grow = blk * 32 + rr * 16 + w;
            const int r = grow & (N1 - 1);
            float rx = u.tk.sx[r], ry = u.tk.sy[r], rz = u.tk.sz[r];
            unsigned long long k[16];
#pragma unroll
            for (int t = 0; t < 16; ++t) {
                int m = t * 64 + lane;            // lane-consecutive: conflict-free
                float v = fabsf(rx * u.tk.sx[m] + ry * u.tk.sy[m] + rz * u.tk.sz[m]);
                k[t] = ((unsigned long long)__float_as_uint(v) << 32)
                     | (unsigned int)(0xFFFFFFFFu - (unsigned int)m);
            }
#pragma unroll
            for (int pass = 0; pass < KNB; ++pass) {
                unsigned long long lm = k[0];
#pragma unroll
                for (int t = 1; t < 16; ++t) lm = (k[t] > lm) ? k[t] : lm;
#pragma unroll
                for (int off = 1; off < 64; off <<= 1) {
                    unsigned long long o = __shfl_xor(lm, off, 64);
                    lm = (o > lm) ? o : lm;
                }
                if (lane == 0) {
                    int idx = (int)(0xFFFFFFFFu - (unsigned int)(lm & 0xFFFFFFFFull));
                    stci(&nbb[grow * KNB + pass], b * N1 + idx);
                }
#pragma unroll
                for (int t = 0; t < 16; ++t) if (k[t] == lm) k[t] = 0;
            }
        }
        // publish indb/nbb so this block's own plain reads (sphere) see them
        asm volatile("s_waitcnt vmcnt(0)" ::: "memory");
        __syncthreads();
    };

    // ================= stage 0 =================
    if (tid < 32) {                               // xyz0 gather (used by NMS)
        int j = blk * 32 + tid;
        int p = P.ind0[j];
        stc(&P.xyz0[j * 3 + 0], P.xyz[p * 3 + 0]);
        stc(&P.xyz0[j * 3 + 1], P.xyz[p * 3 + 1]);
        stc(&P.xyz0[j * 3 + 2], P.xyz[p * 3 + 2]);
    }
    sphere(P.ind0, P.wsS[0], P.bsS[0], P.xs0[0]);
    BAR(1);
    dgcn(P.xs0[0], P.nb0, P.dgWs[0], P.dgWn[0], P.dgB[0], 0, P.xs0[1], false, nullptr, nullptr, nullptr, nullptr);
    BAR(2);
    dgcn(P.xs0[1], P.nb0, P.dgWs[0], P.dgWn[0], P.dgB[0], 1, P.xs0[2], false, nullptr, nullptr, nullptr, nullptr);
    BAR(3);
    dgcn(P.xs0[2], P.nb0, P.dgWs[0], P.dgWn[0], P.dgB[0], 2, P.xs0[3], false, nullptr, nullptr, nullptr, nullptr);
    BAR(4);
    dgcn(P.xs0[3], P.nb0, P.dgWs[0], P.dgWn[0], P.dgB[0], 3, nullptr, true,
         P.dgH[0], P.dgHb[0], P.s0, P.out);
    BAR(5);

    // ===== NMS (block 0 only; s0/xyz0 plain — fresh lines) =====
    if (blk == 0) {
        for (int jj = tid; jj < N0; jj += BLOCK) u.sc[jj] = P.s0[jj];
        __syncthreads();
        for (int it = 0; it < 3; ++it) {
            float bv = -INFINITY; int bi = 0x7fffffff;
            for (int jj = tid; jj < N0; jj += BLOCK) {
                float v = u.sc[jj];
                if (v > bv) { bv = v; bi = jj; }   // strided ascending: first max kept
            }
            rv[tid] = bv; ri[tid] = bi;
            __syncthreads();
            for (int sft = BLOCK / 2; sft > 0; sft >>= 1) {
                if (tid < sft) {
                    float v2 = rv[tid + sft]; int i2 = ri[tid + sft];
                    if (v2 > rv[tid] || (v2 == rv[tid] && i2 < ri[tid])) {
                        rv[tid] = v2; ri[tid] = i2;
                    }
                }
                __syncthreads();
            }
            int sel = ri[0];
            if (tid == 0) {
                stci(&P.anchorA[it], P.ind0[sel]);
                psel[0] = P.xyz0[sel * 3 + 0];
                psel[1] = P.xyz0[sel * 3 + 1];
                psel[2] = P.xyz0[sel * 3 + 2];
            }
            __syncthreads();
            float px = psel[0], py = psel[1], pz = psel[2];
            for (int jj = tid; jj < N0; jj += BLOCK) {
                float d = fabsf(P.xyz0[jj * 3 + 0] * px + P.xyz0[jj * 3 + 1] * py
                              + P.xyz0[jj * 3 + 2] * pz);
                if (d >= COS_T) u.sc[jj] = NEG_INF;
            }
            __syncthreads();
        }
    }

    // blocks >= NACT: arrive at B6 and exit
    if (blk >= NACT) {
        asm volatile("s_waitcnt vmcnt(0)" ::: "memory");
        __syncthreads();
        if (tid == 0)
            __hip_atomic_fetch_add(P.cnt, 1u, __ATOMIC_RELAXED, __HIP_MEMORY_SCOPE_AGENT);
        return;
    }
    BAR(6);

    // ================= stages 1 & 2 (96 blocks x 32 rows) =================
    for (int st = 1; st <= 2; ++st) {
        float* const* xb = (st == 1) ? P.xs1 : P.xs2;
        int* indb = (st == 1) ? P.indb1 : P.indb2;
        int* nbb  = (st == 1) ? P.nbb1  : P.nbb2;
        const int* anc = (st == 1) ? P.anchorA : P.anchorB;
        const int ep = (st == 1) ? 6 : 12;

        topk(P.isc[st - 1], anc, indb, nbb);
        sphere(indb, P.wsS[st], P.bsS[st], xb[0]);
        BAR(ep + 1);
        dgcn(xb[0], nbb, P.dgWs[st], P.dgWn[st], P.dgB[st], 0, xb[1], false, nullptr, nullptr, nullptr, nullptr);
        BAR(ep + 2);
        dgcn(xb[1], nbb, P.dgWs[st], P.dgWn[st], P.dgB[st], 1, xb[2], false, nullptr, nullptr, nullptr, nullptr);
        BAR(ep + 3);
        dgcn(xb[2], nbb, P.dgWs[st], P.dgWn[st], P.dgB[st], 2, xb[3], false, nullptr, nullptr, nullptr, nullptr);
        BAR(ep + 4);
        dgcn(xb[3], nbb, P.dgWs[st], P.dgWn[st], P.dgB[st], 3, nullptr, true,
             P.dgH[st], P.dgHb[st], (st == 1) ? P.sbr : nullptr,
             P.out + N0 + (st - 1) * 3 * N1);
        if (st == 1) {
            BAR(11);
            if (blk < 3) {    // per-branch argmax over sbr (plain, fresh)
                float bv = P.sbr[blk * N1 + tid];
                int bi = tid;
                rv[tid] = bv; ri[tid] = bi;
                __syncthreads();
                for (int sft = BLOCK / 2; sft > 0; sft >>= 1) {
                    if (tid < sft) {
                        float v2 = rv[tid + sft]; int i2 = ri[tid + sft];
                        if (v2 > rv[tid] || (v2 == rv[tid] && i2 < ri[tid])) {
                            rv[tid] = v2; ri[tid] = i2;
                        }
                    }
                    __syncthreads();
                }
                if (tid == 0) stci(&P.anchorB[blk], P.indb1[blk * N1 + ri[0]]);
            }
            BAR(12);
        }
    }
}

extern "C" void kernel_launch(void* const* d_in, const int* in_sizes, int n_in,
                              void* d_out, int out_size, void* d_ws, size_t ws_size,
                              hipStream_t stream) {
    MegaParams hp;
    hp.feat = (const float*)d_in[0];
    hp.xyz  = (const float*)d_in[1];
    hp.wsS[0] = (const float*)d_in[2];  hp.bsS[0] = (const float*)d_in[3];
    hp.wsS[1] = (const float*)d_in[4];  hp.bsS[1] = (const float*)d_in[5];
    hp.wsS[2] = (const float*)d_in[6];  hp.bsS[2] = (const float*)d_in[7];
    hp.dgWs[0] = (const float*)d_in[8];  hp.dgWn[0] = (const float*)d_in[9];
    hp.dgB[0]  = (const float*)d_in[10]; hp.dgH[0]  = (const float*)d_in[11];
    hp.dgHb[0] = (const float*)d_in[12];
    hp.dgWs[1] = (const float*)d_in[13]; hp.dgWn[1] = (const float*)d_in[14];
    hp.dgB[1]  = (const float*)d_in[15]; hp.dgH[1]  = (const float*)d_in[16];
    hp.dgHb[1] = (const float*)d_in[17];
    hp.dgWs[2] = (const float*)d_in[18]; hp.dgWn[2] = (const float*)d_in[19];
    hp.dgB[2]  = (const float*)d_in[20]; hp.dgH[2]  = (const float*)d_in[21];
    hp.dgHb[2] = (const float*)d_in[22];
    const int* edge0 = (const int*)d_in[23];
    hp.nb0  = edge0 + N0 * KNB;
    hp.ind0 = (const int*)d_in[24];
    hp.isc[0] = (const int*)d_in[25];
    hp.isc[1] = (const int*)d_in[26];
    hp.out = (float*)d_out;

    float* f = (float*)d_ws;
    size_t o = 0;
    auto takeF = [&](size_t n) { float* p = f + o; o += n; return p; };

    // small, always-distinct buffers first
    hp.s0   = takeF(N0);
    hp.sbr  = takeF(3 * N1);
    hp.xyz0 = takeF((size_t)N0 * 3);
    o = (o + 63) & ~(size_t)63;
    hp.anchorA = (int*)takeF(64);                // own 256B line
    hp.anchorB = (int*)takeF(64);                // own 256B line
    hp.indb1 = (int*)takeF(3 * N1);
    hp.nbb1  = (int*)takeF(3 * N1 * KNB);
    hp.indb2 = (int*)takeF(3 * N1);
    hp.nbb2  = (int*)takeF(3 * N1 * KNB);
    o = (o + 63) & ~(size_t)63;
    hp.cnt  = (unsigned*)takeF(64);              // own 256B line
    hp.flag = (unsigned*)takeF(64);              // own 256B line
    unsigned* ctrBase = hp.cnt;

    // activation buffers: distinct per phase if ws allows (fast mode)
    size_t needFast = (o + 4 * (size_t)N0 * C_H + 8 * (size_t)(3 * N1) * C_H) * sizeof(float);
    if (ws_size >= needFast) {
        hp.actCoh = 0;
        for (int i = 0; i < 4; ++i) hp.xs0[i] = takeF((size_t)N0 * C_H);
        for (int i = 0; i < 4; ++i) hp.xs1[i] = takeF((size_t)(3 * N1) * C_H);
        for (int i = 0; i < 4; ++i) hp.xs2[i] = takeF((size_t)(3 * N1) * C_H);
    } else {
        hp.actCoh = 1;                           // round-4-proven sc1 fallback
        float* xA = takeF((size_t)N0 * C_H);
        float* xB = takeF((size_t)N0 * C_H);
        for (int i = 0; i < 4; ++i) {
            hp.xs0[i] = (i & 1) ? xB : xA;
            hp.xs1[i] = (i & 1) ? xB : xA;
            hp.xs2[i] = (i & 1) ? xB : xA;
        }
    }

    hipMemsetAsync((void*)ctrBase, 0, 512, stream);   // reset cnt + flag
    mega_kernel<<<dim3(GRID), dim3(BLOCK), 0, stream>>>(hp);
}

// Round 6
// 250.584 us; speedup vs baseline: 12.7193x; 1.1673x over previous
//
#include <hip/hip_runtime.h>
#include <math.h>

#define N_TOTAL 32768
#define N0 8192
#define N1 1024
#define KNB 8
#define C_IN 128
#define C_H 64
#define COS_T 0.999f
#define NEG_INF -1e30f
#define GRID 512
#define BLOCK 512
#define NACT 384      // blocks that stay alive after stage 0

// sc1 agent-scope accessors: write-through to the Infinity-Cache coherence
// point. Producers of cross-block data STORE with these; consumers use PLAIN
// cached loads (safe: every such buffer is written-once-then-read within this
// launch, and its lines are never L2-cached before the write).
__device__ __forceinline__ float ldc(const float* p) {
    return __hip_atomic_load(p, __ATOMIC_RELAXED, __HIP_MEMORY_SCOPE_AGENT);
}
__device__ __forceinline__ void stc(float* p, float v) {
    __hip_atomic_store(p, v, __ATOMIC_RELAXED, __HIP_MEMORY_SCOPE_AGENT);
}
__device__ __forceinline__ void stci(int* p, int v) {
    __hip_atomic_store(p, v, __ATOMIC_RELAXED, __HIP_MEMORY_SCOPE_AGENT);
}

struct MegaParams {
    const float* feat;
    const float* xyz;
    const float* wsS[3];
    const float* bsS[3];
    const float* dgWs[3];
    const float* dgWn[3];
    const float* dgB[3];
    const float* dgH[3];
    const float* dgHb[3];
    const int* nb0;
    const int* ind0;
    const int* isc[2];
    float* out;
    float* xs0[4];
    float* xs1[4];
    float* xs2[4];
    float* s0;
    float* sbr;
    float* xyz0;
    float* featT;
    int* anchorA;
    int* anchorB;
    int* indb1; int* nbb1;
    int* indb2; int* nbb2;
    unsigned* cnt;
    unsigned* flag;
    int tr;          // 1 = featT transpose path
    int actCoh;      // 1 = small-ws fallback: activations via sc1 loads
};

__global__ void __launch_bounds__(BLOCK, 4) mega_kernel(MegaParams P) {
    const int blk = blockIdx.x;
    const int tid = threadIdx.x;
    const int w = tid >> 6;      // wave id 0..7
    const int lane = tid & 63;   // channel

    __shared__ union {
        float tt[64][129];                                        // 33.0KB (transpose)
        struct { float wt[C_IN * 65]; float col[8][C_IN]; } sp;   // 37.3KB (sphere)
        struct { float ws[C_H * C_H]; float wn[C_H * C_H];
                 float xw[8][C_H]; float aw[8][C_H]; } dg;        // 36KB   (dgcn)
        struct { float sx[N1]; float sy[N1]; float sz[N1]; } tk;  // 12KB   (topk)
        float sc[N0];                                             // 32KB   (NMS)
    } u;
    __shared__ float rv[BLOCK];
    __shared__ int ri[BLOCK];
    __shared__ float psel[3];

    // Grid barrier: drain sc1 stores -> 1 RMW arrive/block -> block 0 polls
    // counter, broadcasts epoch via flag; others poll the flag line. No
    // cache-wide fences anywhere — caches stay warm.
    auto BAR = [&](int e) {
        asm volatile("s_waitcnt vmcnt(0)" ::: "memory");
        __syncthreads();
        if (tid == 0) {
            __hip_atomic_fetch_add(P.cnt, 1u, __ATOMIC_RELAXED, __HIP_MEMORY_SCOPE_AGENT);
            if (blk == 0) {
                unsigned tgt = (e <= 6) ? (unsigned)(GRID * e)
                                        : (unsigned)(GRID * 6 + NACT * (e - 6));
                while (__hip_atomic_load(P.cnt, __ATOMIC_RELAXED, __HIP_MEMORY_SCOPE_AGENT) < tgt)
                    __builtin_amdgcn_s_sleep(2);
                __hip_atomic_store(P.flag, (unsigned)e, __ATOMIC_RELAXED, __HIP_MEMORY_SCOPE_AGENT);
            } else {
                while (__hip_atomic_load(P.flag, __ATOMIC_RELAXED, __HIP_MEMORY_SCOPE_AGENT) < (unsigned)e)
                    __builtin_amdgcn_s_sleep(2);
            }
        }
        __syncthreads();
    };

    // ---- sphere: npb nodes/block, W^T staged in LDS (pad 65) ----
    auto sphere = [&](int npb, const int* ind, const float* W, const float* bv,
                      float* xout) {
        __syncthreads();                          // union handoff
        const float4* W4 = (const float4*)W;
        for (int i4 = tid; i4 < C_H * C_IN / 4; i4 += BLOCK) {
            float4 v = W4[i4];
            int c = (i4 * 4) >> 7, k = (i4 * 4) & 127;   // 4 consec k, same c
            u.sp.wt[(k + 0) * 65 + c] = v.x;
            u.sp.wt[(k + 1) * 65 + c] = v.y;
            u.sp.wt[(k + 2) * 65 + c] = v.z;
            u.sp.wt[(k + 3) * 65 + c] = v.w;
        }
        __syncthreads();
        for (int it = 0; it < npb / 8; ++it) {
            int j = blk * npb + it * 8 + w;
            int p = ind[j];
            if (P.tr) {
                u.sp.col[w][lane]      = P.featT[(size_t)p * C_IN + lane];
                u.sp.col[w][lane + 64] = P.featT[(size_t)p * C_IN + lane + 64];
            } else {
                u.sp.col[w][lane]      = P.feat[(size_t)lane * N_TOTAL + p];
                u.sp.col[w][lane + 64] = P.feat[(size_t)(lane + 64) * N_TOTAL + p];
            }
            float acc = bv[lane];
#pragma unroll 8
            for (int k = 0; k < C_IN; ++k)
                acc += u.sp.col[w][k] * u.sp.wt[k * 65 + lane];
            stc(&xout[(size_t)j * C_H + lane], acc);
        }
    };

    // ---- one DGCN layer: npb nodes/block; weights staged in LDS ----
    auto dgcn = [&](int npb, const float* xin, const int* nbp,
                    const float* Wsl, const float* Wnl, const float* bias, int l,
                    float* xout, bool last, const float* head, const float* hb,
                    float* sdst, float* odst) {
        __syncthreads();                          // union handoff
        const float4* Ws4 = (const float4*)(Wsl + l * C_H * C_H);
        const float4* Wn4 = (const float4*)(Wnl + l * C_H * C_H);
        float4* dws = (float4*)u.dg.ws;
        float4* dwn = (float4*)u.dg.wn;
        for (int i = tid; i < C_H * C_H / 4; i += BLOCK) {
            dws[i] = Ws4[i];
            dwn[i] = Wn4[i];
        }
        __syncthreads();
        for (int ni = w; ni < npb; ni += 8) {
            int j = blk * npb + ni;
            float xv, a = 0.f;
            if (!P.actCoh) {
                xv = xin[(size_t)j * C_H + lane];
#pragma unroll
                for (int t = 0; t < KNB; ++t) {
                    int q = nbp[j * KNB + t];
                    a += xin[(size_t)q * C_H + lane];
                }
            } else {
                xv = ldc(&xin[(size_t)j * C_H + lane]);
#pragma unroll
                for (int t = 0; t < KNB; ++t) {
                    int q = nbp[j * KNB + t];
                    a += ldc(&xin[(size_t)q * C_H + lane]);
                }
            }
            u.dg.xw[w][lane] = xv;
            u.dg.aw[w][lane] = a * (1.0f / KNB);
            float acc = bias[l * C_H + lane];
#pragma unroll 8
            for (int k = 0; k < C_H; ++k)
                acc += u.dg.xw[w][k] * u.dg.ws[k * C_H + lane]
                     + u.dg.aw[w][k] * u.dg.wn[k * C_H + lane];
            acc = fmaxf(acc, 0.f);
            if (!last) {
                stc(&xout[(size_t)j * C_H + lane], acc);
            } else {
                float v = acc * head[lane];
#pragma unroll
                for (int off = 32; off > 0; off >>= 1) v += __shfl_down(v, off, 64);
                if (lane == 0) {
                    float s = v + hb[0];
                    if (sdst) stc(&sdst[j], s);
                    odst[j] = 1.f / (1.f + expf(-s));   // plain; flushed at kernel end
                }
            }
        }
    };

    // ---- fused gather + per-row stable top-8; 8 rows/block (NACT blocks) ----
    auto topk = [&](const int* isc, const int* anc, int* indb, int* nbb) {
        __syncthreads();                          // union handoff
        const int b = blk >> 7;                   // branch (128 blocks per branch)
        const int a = anc[b];                     // plain (fresh line)
        const int* row = isc + (size_t)a * N1;
#pragma unroll
        for (int mm = 0; mm < 2; ++mm) {
            int m = mm * BLOCK + tid;
            int pp = row[m];
            u.tk.sx[m] = P.xyz[pp * 3 + 0];
            u.tk.sy[m] = P.xyz[pp * 3 + 1];
            u.tk.sz[m] = P.xyz[pp * 3 + 2];
        }
        if (tid < 8) {
            int grow = blk * 8 + tid;
            stci(&indb[grow], row[grow & (N1 - 1)]);
        }
        __syncthreads();
        {
            const int grow = blk * 8 + w;         // one row per wave
            const int r = grow & (N1 - 1);
            float rx = u.tk.sx[r], ry = u.tk.sy[r], rz = u.tk.sz[r];
            unsigned long long k[16];
#pragma unroll
            for (int t = 0; t < 16; ++t) {
                int m = t * 64 + lane;            // lane-consecutive: conflict-free
                float v = fabsf(rx * u.tk.sx[m] + ry * u.tk.sy[m] + rz * u.tk.sz[m]);
                k[t] = ((unsigned long long)__float_as_uint(v) << 32)
                     | (unsigned int)(0xFFFFFFFFu - (unsigned int)m);
            }
#pragma unroll
            for (int pass = 0; pass < KNB; ++pass) {
                unsigned long long lm = k[0];
#pragma unroll
                for (int t = 1; t < 16; ++t) lm = (k[t] > lm) ? k[t] : lm;
#pragma unroll
                for (int off = 1; off < 64; off <<= 1) {
                    unsigned long long o = __shfl_xor(lm, off, 64);
                    lm = (o > lm) ? o : lm;
                }
                if (lane == 0) {
                    int idx = (int)(0xFFFFFFFFu - (unsigned int)(lm & 0xFFFFFFFFull));
                    stci(&nbb[grow * KNB + pass], b * N1 + idx);
                }
#pragma unroll
                for (int t = 0; t < 16; ++t) if (k[t] == lm) k[t] = 0;
            }
        }
        // publish indb so this block's own plain reads (sphere) see them
        asm volatile("s_waitcnt vmcnt(0)" ::: "memory");
        __syncthreads();
    };

    // ===== epoch 1: feat transpose (64 cols/block) + xyz0 gather =====
    if (P.tr) {
        const int g0 = blk * 64;
        const int col = tid & 63, rowH = tid >> 6;    // 64 cols x 8 ch-rows/pass
        for (int c0 = 0; c0 < C_IN; c0 += 8) {
            int c = c0 + rowH;
            u.tt[col][c] = P.feat[(size_t)c * N_TOTAL + g0 + col];   // coalesced
        }
        __syncthreads();
        for (int i = tid; i < 64 * C_IN; i += BLOCK) {
            int cc = i >> 7, c = i & 127;
            stc(&P.featT[(size_t)(g0 + cc) * C_IN + c], u.tt[cc][c]); // coalesced
        }
    }
    if (tid < 16) {
        int j = blk * 16 + tid;
        int p = P.ind0[j];
        stc(&P.xyz0[j * 3 + 0], P.xyz[p * 3 + 0]);
        stc(&P.xyz0[j * 3 + 1], P.xyz[p * 3 + 1]);
        stc(&P.xyz0[j * 3 + 2], P.xyz[p * 3 + 2]);
    }
    BAR(1);

    // ===== stage 0 (16 nodes/block) =====
    sphere(16, P.ind0, P.wsS[0], P.bsS[0], P.xs0[0]);
    BAR(2);
    dgcn(16, P.xs0[0], P.nb0, P.dgWs[0], P.dgWn[0], P.dgB[0], 0, P.xs0[1], false, nullptr, nullptr, nullptr, nullptr);
    BAR(3);
    dgcn(16, P.xs0[1], P.nb0, P.dgWs[0], P.dgWn[0], P.dgB[0], 1, P.xs0[2], false, nullptr, nullptr, nullptr, nullptr);
    BAR(4);
    dgcn(16, P.xs0[2], P.nb0, P.dgWs[0], P.dgWn[0], P.dgB[0], 2, P.xs0[3], false, nullptr, nullptr, nullptr, nullptr);
    BAR(5);
    dgcn(16, P.xs0[3], P.nb0, P.dgWs[0], P.dgWn[0], P.dgB[0], 3, nullptr, true,
         P.dgH[0], P.dgHb[0], P.s0, P.out);

    // blocks >= NACT: arrive at B6 and exit
    if (blk >= NACT) {
        asm volatile("s_waitcnt vmcnt(0)" ::: "memory");
        __syncthreads();
        if (tid == 0)
            __hip_atomic_fetch_add(P.cnt, 1u, __ATOMIC_RELAXED, __HIP_MEMORY_SCOPE_AGENT);
        return;
    }
    BAR(6);

    // ===== NMS (block 0 only; s0/xyz0 plain — fresh lines) =====
    if (blk == 0) {
        for (int jj = tid; jj < N0; jj += BLOCK) u.sc[jj] = P.s0[jj];
        __syncthreads();
        for (int it = 0; it < 3; ++it) {
            float bv = -INFINITY; int bi = 0x7fffffff;
            for (int jj = tid; jj < N0; jj += BLOCK) {
                float v = u.sc[jj];
                if (v > bv) { bv = v; bi = jj; }   // strided ascending: first max kept
            }
            rv[tid] = bv; ri[tid] = bi;
            __syncthreads();
            for (int sft = BLOCK / 2; sft > 0; sft >>= 1) {
                if (tid < sft) {
                    float v2 = rv[tid + sft]; int i2 = ri[tid + sft];
                    if (v2 > rv[tid] || (v2 == rv[tid] && i2 < ri[tid])) {
                        rv[tid] = v2; ri[tid] = i2;
                    }
                }
                __syncthreads();
            }
            int sel = ri[0];
            if (tid == 0) {
                stci(&P.anchorA[it], P.ind0[sel]);
                psel[0] = P.xyz0[sel * 3 + 0];
                psel[1] = P.xyz0[sel * 3 + 1];
                psel[2] = P.xyz0[sel * 3 + 2];
            }
            __syncthreads();
            float px = psel[0], py = psel[1], pz = psel[2];
            for (int jj = tid; jj < N0; jj += BLOCK) {
                float d = fabsf(P.xyz0[jj * 3 + 0] * px + P.xyz0[jj * 3 + 1] * py
                              + P.xyz0[jj * 3 + 2] * pz);
                if (d >= COS_T) u.sc[jj] = NEG_INF;
            }
            __syncthreads();
        }
    }
    BAR(7);

    // ===== stages 1 & 2 (384 blocks x 8 nodes) =====
    for (int st = 1; st <= 2; ++st) {
        float* const* xb = (st == 1) ? P.xs1 : P.xs2;
        int* indb = (st == 1) ? P.indb1 : P.indb2;
        int* nbb  = (st == 1) ? P.nbb1  : P.nbb2;
        const int* anc = (st == 1) ? P.anchorA : P.anchorB;
        const int ep = (st == 1) ? 7 : 13;

        topk(P.isc[st - 1], anc, indb, nbb);
        sphere(8, indb, P.wsS[st], P.bsS[st], xb[0]);
        BAR(ep + 1);
        dgcn(8, xb[0], nbb, P.dgWs[st], P.dgWn[st], P.dgB[st], 0, xb[1], false, nullptr, nullptr, nullptr, nullptr);
        BAR(ep + 2);
        dgcn(8, xb[1], nbb, P.dgWs[st], P.dgWn[st], P.dgB[st], 1, xb[2], false, nullptr, nullptr, nullptr, nullptr);
        BAR(ep + 3);
        dgcn(8, xb[2], nbb, P.dgWs[st], P.dgWn[st], P.dgB[st], 2, xb[3], false, nullptr, nullptr, nullptr, nullptr);
        BAR(ep + 4);
        dgcn(8, xb[3], nbb, P.dgWs[st], P.dgWn[st], P.dgB[st], 3, nullptr, true,
             P.dgH[st], P.dgHb[st], (st == 1) ? P.sbr : nullptr,
             P.out + N0 + (st - 1) * 3 * N1);
        if (st == 1) {
            BAR(12);
            if (blk < 3) {    // per-branch argmax over sbr (plain, fresh)
                float bv = -INFINITY; int bi = 0x7fffffff;
                for (int m = tid; m < N1; m += BLOCK) {
                    float v = P.sbr[blk * N1 + m];
                    if (v > bv) { bv = v; bi = m; }   // ascending: first max kept
                }
                rv[tid] = bv; ri[tid] = bi;
                __syncthreads();
                for (int sft = BLOCK / 2; sft > 0; sft >>= 1) {
                    if (tid < sft) {
                        float v2 = rv[tid + sft]; int i2 = ri[tid + sft];
                        if (v2 > rv[tid] || (v2 == rv[tid] && i2 < ri[tid])) {
                            rv[tid] = v2; ri[tid] = i2;
                        }
                    }
                    __syncthreads();
                }
                if (tid == 0) stci(&P.anchorB[blk], P.indb1[blk * N1 + ri[0]]);
            }
            BAR(13);
        }
    }
}

extern "C" void kernel_launch(void* const* d_in, const int* in_sizes, int n_in,
                              void* d_out, int out_size, void* d_ws, size_t ws_size,
                              hipStream_t stream) {
    MegaParams hp;
    hp.feat = (const float*)d_in[0];
    hp.xyz  = (const float*)d_in[1];
    hp.wsS[0] = (const float*)d_in[2];  hp.bsS[0] = (const float*)d_in[3];
    hp.wsS[1] = (const float*)d_in[4];  hp.bsS[1] = (const float*)d_in[5];
    hp.wsS[2] = (const float*)d_in[6];  hp.bsS[2] = (const float*)d_in[7];
    hp.dgWs[0] = (const float*)d_in[8];  hp.dgWn[0] = (const float*)d_in[9];
    hp.dgB[0]  = (const float*)d_in[10]; hp.dgH[0]  = (const float*)d_in[11];
    hp.dgHb[0] = (const float*)d_in[12];
    hp.dgWs[1] = (const float*)d_in[13]; hp.dgWn[1] = (const float*)d_in[14];
    hp.dgB[1]  = (const float*)d_in[15]; hp.dgH[1]  = (const float*)d_in[16];
    hp.dgHb[1] = (const float*)d_in[17];
    hp.dgWs[2] = (const float*)d_in[18]; hp.dgWn[2] = (const float*)d_in[19];
    hp.dgB[2]  = (const float*)d_in[20]; hp.dgH[2]  = (const float*)d_in[21];
    hp.dgHb[2] = (const float*)d_in[22];
    const int* edge0 = (const int*)d_in[23];
    hp.nb0  = edge0 + N0 * KNB;
    hp.ind0 = (const int*)d_in[24];
    hp.isc[0] = (const int*)d_in[25];
    hp.isc[1] = (const int*)d_in[26];
    hp.out = (float*)d_out;

    float* f = (float*)d_ws;
    size_t o = 0;
    auto takeF = [&](size_t n) { float* p = f + o; o += n; return p; };

    hp.s0   = takeF(N0);
    hp.sbr  = takeF(3 * N1);
    hp.xyz0 = takeF((size_t)N0 * 3);
    o = (o + 63) & ~(size_t)63;
    hp.anchorA = (int*)takeF(64);
    hp.anchorB = (int*)takeF(64);
    hp.indb1 = (int*)takeF(3 * N1);
    hp.nbb1  = (int*)takeF(3 * N1 * KNB);
    hp.indb2 = (int*)takeF(3 * N1);
    hp.nbb2  = (int*)takeF(3 * N1 * KNB);
    o = (o + 63) & ~(size_t)63;
    hp.cnt  = (unsigned*)takeF(64);
    hp.flag = (unsigned*)takeF(64);
    unsigned* ctrBase = hp.cnt;

    // activation buffers: distinct per phase if ws allows
    size_t needFast = (o + 4 * (size_t)N0 * C_H + 8 * (size_t)(3 * N1) * C_H) * sizeof(float);
    if (ws_size >= needFast) {
        hp.actCoh = 0;
        for (int i = 0; i < 4; ++i) hp.xs0[i] = takeF((size_t)N0 * C_H);
        for (int i = 0; i < 4; ++i) hp.xs1[i] = takeF((size_t)(3 * N1) * C_H);
        for (int i = 0; i < 4; ++i) hp.xs2[i] = takeF((size_t)(3 * N1) * C_H);
    } else {
        hp.actCoh = 1;
        float* xA = takeF((size_t)N0 * C_H);
        float* xB = takeF((size_t)N0 * C_H);
        for (int i = 0; i < 4; ++i) {
            hp.xs0[i] = (i & 1) ? xB : xA;
            hp.xs1[i] = (i & 1) ? xB : xA;
            hp.xs2[i] = (i & 1) ? xB : xA;
        }
    }

    // featT if it fits
    size_t needTr = (o + (size_t)N_TOTAL * C_IN) * sizeof(float);
    if (ws_size >= needTr) {
        hp.tr = 1;
        hp.featT = takeF((size_t)N_TOTAL * C_IN);
    } else {
        hp.tr = 0;
        hp.featT = nullptr;
    }

    hipMemsetAsync((void*)ctrBase, 0, 512, stream);
    mega_kernel<<<dim3(GRID), dim3(BLOCK), 0, stream>>>(hp);
}

// Round 7
// 189.174 us; speedup vs baseline: 16.8482x; 1.3246x over previous
//
#include <hip/hip_runtime.h>
#include <math.h>

#define N_TOTAL 32768
#define N0 8192
#define N1 1024
#define KNB 8
#define C_IN 128
#define C_H 64
#define COS_T 0.999f
#define NEG_INF -1e30f
#define GRID 512
#define BLOCK 512
#define NACT 384      // blocks that stay alive after stage 0
#define SLOT_DONE 0x7fffffffu

// sc1 agent-scope accessors: write-through to the Infinity-Cache coherence
// point. Producers of cross-block data STORE with these; consumers use PLAIN
// cached loads (safe: each buffer is written-once-then-read in this launch,
// and dispatch start invalidates L2 — proven over rounds 4-6).
__device__ __forceinline__ void stc(float* p, float v) {
    __hip_atomic_store(p, v, __ATOMIC_RELAXED, __HIP_MEMORY_SCOPE_AGENT);
}
__device__ __forceinline__ void stci(int* p, int v) {
    __hip_atomic_store(p, v, __ATOMIC_RELAXED, __HIP_MEMORY_SCOPE_AGENT);
}
__device__ __forceinline__ float ldc(const float* p) {
    return __hip_atomic_load(p, __ATOMIC_RELAXED, __HIP_MEMORY_SCOPE_AGENT);
}

struct MegaParams {
    const float* feat;
    const float* xyz;
    const float* wsS[3];
    const float* bsS[3];
    const float* dgWs[3];
    const float* dgWn[3];
    const float* dgB[3];
    const float* dgH[3];
    const float* dgHb[3];
    const int* nb0;
    const int* ind0;
    const int* isc[2];
    float* out;
    float* xs0[4];
    float* xs1[4];
    float* xs2[4];
    float* s0;
    float* sbr;
    float* xyz0;
    float* featT;
    int* anchorA;
    int* anchorB;
    int* indb1; int* nbb1;
    int* indb2; int* nbb2;
    unsigned* slot;    // [GRID] per-block arrival slots (no RMW contention)
    unsigned* flag;    // 8 replicated epoch lines (stride 16 words)
    int tr;
    int actCoh;
};

__global__ void __launch_bounds__(BLOCK, 4) mega_kernel(MegaParams P) {
    const int blk = blockIdx.x;
    const int tid = threadIdx.x;
    const int w = tid >> 6;      // wave id 0..7
    const int lane = tid & 63;   // channel

    __shared__ alignas(16) union {
        float tt[64][129];                                        // 33.0KB (transpose)
        struct { float wt[C_H * 132]; float col[8][C_IN]; } sp;   // 37.9KB (sphere)
        struct { float ws[C_H * 68]; float wn[C_H * 68];
                 float xw[8][C_H]; float aw[8][C_H]; } dg;        // 38.9KB (dgcn)
        struct { float sx[N1]; float sy[N1]; float sz[N1]; } tk;  // 12KB   (topk)
        float sc[N0];                                             // 32KB   (NMS)
    } u;
    __shared__ float rv[BLOCK];
    __shared__ int ri[BLOCK];
    __shared__ float psel[3];

    // Contention-free grid barrier:
    //  arrive : leader sc1-STOREs epoch to its own slot (no RMW, no contention)
    //  detect : block 0's threads poll one slot each in parallel
    //  release: block 0 writes 8 replicated flag lines; leaders poll their replica
    auto BAR = [&](int e) {
        asm volatile("s_waitcnt vmcnt(0)" ::: "memory");
        __syncthreads();
        if (blk == 0) {
            if (tid > 0 && tid < GRID) {
                while (__hip_atomic_load(&P.slot[tid], __ATOMIC_RELAXED,
                                         __HIP_MEMORY_SCOPE_AGENT) < (unsigned)e)
                    __builtin_amdgcn_s_sleep(1);
            }
            __syncthreads();
            if (tid < 8)
                __hip_atomic_store(&P.flag[tid * 16], (unsigned)e, __ATOMIC_RELAXED,
                                   __HIP_MEMORY_SCOPE_AGENT);
            __syncthreads();
        } else {
            if (tid == 0) {
                __hip_atomic_store(&P.slot[blk], (unsigned)e, __ATOMIC_RELAXED,
                                   __HIP_MEMORY_SCOPE_AGENT);
                while (__hip_atomic_load(&P.flag[(blk & 7) * 16], __ATOMIC_RELAXED,
                                         __HIP_MEMORY_SCOPE_AGENT) < (unsigned)e)
                    __builtin_amdgcn_s_sleep(2);
            }
            __syncthreads();
        }
    };

    // ---- sphere: npb nodes/block; W staged channel-major wt[c*132+k]
    // ---- (33-granule odd stride: b128 reads are bank-group uniform) ----
    auto sphere = [&](int npb, const int* ind, const float* W, const float* bv,
                      float* xout) {
        __syncthreads();                          // union handoff
        const float4* W4 = (const float4*)W;
        for (int i4 = tid; i4 < C_H * C_IN / 4; i4 += BLOCK) {
            int c = i4 >> 5, kg = i4 & 31;        // row c, granule kg
            *(float4*)&u.sp.wt[c * 132 + kg * 4] = W4[i4];
        }
        __syncthreads();
        for (int it = 0; it < npb / 8; ++it) {
            int j = blk * npb + it * 8 + w;
            int p = ind[j];
            if (P.tr) {
                u.sp.col[w][lane]      = P.featT[(size_t)p * C_IN + lane];
                u.sp.col[w][lane + 64] = P.featT[(size_t)p * C_IN + lane + 64];
            } else {
                u.sp.col[w][lane]      = P.feat[(size_t)lane * N_TOTAL + p];
                u.sp.col[w][lane + 64] = P.feat[(size_t)(lane + 64) * N_TOTAL + p];
            }
            float acc = bv[lane];
#pragma unroll
            for (int k4 = 0; k4 < C_IN / 4; ++k4) {
                float4 cv = *(const float4*)&u.sp.col[w][k4 * 4];
                float4 wv = *(const float4*)&u.sp.wt[lane * 132 + k4 * 4];
                acc += cv.x * wv.x;
                acc += cv.y * wv.y;
                acc += cv.z * wv.z;
                acc += cv.w * wv.w;
            }
            stc(&xout[(size_t)j * C_H + lane], acc);
        }
    };

    // ---- one DGCN layer: npb nodes/block; weights channel-major ws[c*68+k] ----
    auto dgcn = [&](int npb, const float* xin, const int* nbp,
                    const float* Wsl, const float* Wnl, const float* bias, int l,
                    float* xout, bool last, const float* head, const float* hb,
                    float* sdst, float* odst) {
        __syncthreads();                          // union handoff
        const float* Ws_ = Wsl + l * C_H * C_H;
        const float* Wn_ = Wnl + l * C_H * C_H;
        for (int i = tid; i < C_H * C_H; i += BLOCK) {
            int k = i >> 6, c = i & 63;           // coalesced read, transposed write
            u.dg.ws[c * 68 + k] = Ws_[i];
            u.dg.wn[c * 68 + k] = Wn_[i];
        }
        __syncthreads();
        for (int ni = w; ni < npb; ni += 8) {
            int j = blk * npb + ni;
            float xv, a = 0.f;
            if (!P.actCoh) {
                xv = xin[(size_t)j * C_H + lane];
#pragma unroll
                for (int t = 0; t < KNB; ++t) {
                    int q = nbp[j * KNB + t];
                    a += xin[(size_t)q * C_H + lane];
                }
            } else {
                xv = ldc(&xin[(size_t)j * C_H + lane]);
#pragma unroll
                for (int t = 0; t < KNB; ++t) {
                    int q = nbp[j * KNB + t];
                    a += ldc(&xin[(size_t)q * C_H + lane]);
                }
            }
            u.dg.xw[w][lane] = xv;
            u.dg.aw[w][lane] = a * (1.0f / KNB);
            float acc = bias[l * C_H + lane];
#pragma unroll
            for (int k4 = 0; k4 < C_H / 4; ++k4) {
                float4 xv4 = *(const float4*)&u.dg.xw[w][k4 * 4];
                float4 av4 = *(const float4*)&u.dg.aw[w][k4 * 4];
                float4 wsv = *(const float4*)&u.dg.ws[lane * 68 + k4 * 4];
                float4 wnv = *(const float4*)&u.dg.wn[lane * 68 + k4 * 4];
                acc += xv4.x * wsv.x + av4.x * wnv.x;
                acc += xv4.y * wsv.y + av4.y * wnv.y;
                acc += xv4.z * wsv.z + av4.z * wnv.z;
                acc += xv4.w * wsv.w + av4.w * wnv.w;
            }
            acc = fmaxf(acc, 0.f);
            if (!last) {
                stc(&xout[(size_t)j * C_H + lane], acc);
            } else {
                float v = acc * head[lane];
#pragma unroll
                for (int off = 32; off > 0; off >>= 1) v += __shfl_down(v, off, 64);
                if (lane == 0) {
                    float s = v + hb[0];
                    if (sdst) stc(&sdst[j], s);
                    odst[j] = 1.f / (1.f + expf(-s));   // plain; flushed at kernel end
                }
            }
        }
    };

    // ---- fused gather + per-row stable top-8; 8 rows/block (NACT blocks) ----
    auto topk = [&](const int* isc, const int* anc, int* indb, int* nbb) {
        __syncthreads();                          // union handoff
        const int b = blk >> 7;                   // branch (128 blocks per branch)
        const int a = anc[b];                     // plain (fresh line)
        const int* row = isc + (size_t)a * N1;
#pragma unroll
        for (int mm = 0; mm < 2; ++mm) {
            int m = mm * BLOCK + tid;
            int pp = row[m];
            u.tk.sx[m] = P.xyz[pp * 3 + 0];
            u.tk.sy[m] = P.xyz[pp * 3 + 1];
            u.tk.sz[m] = P.xyz[pp * 3 + 2];
        }
        if (tid < 8) {
            int grow = blk * 8 + tid;
            stci(&indb[grow], row[grow & (N1 - 1)]);
        }
        __syncthreads();
        {
            const int grow = blk * 8 + w;         // one row per wave
            const int r = grow & (N1 - 1);
            float rx = u.tk.sx[r], ry = u.tk.sy[r], rz = u.tk.sz[r];
            unsigned long long k[16];
#pragma unroll
            for (int t = 0; t < 16; ++t) {
                int m = t * 64 + lane;            // lane-consecutive: conflict-free
                float v = fabsf(rx * u.tk.sx[m] + ry * u.tk.sy[m] + rz * u.tk.sz[m]);
                k[t] = ((unsigned long long)__float_as_uint(v) << 32)
                     | (unsigned int)(0xFFFFFFFFu - (unsigned int)m);
            }
#pragma unroll
            for (int pass = 0; pass < KNB; ++pass) {
                unsigned long long lm = k[0];
#pragma unroll
                for (int t = 1; t < 16; ++t) lm = (k[t] > lm) ? k[t] : lm;
#pragma unroll
                for (int off = 1; off < 64; off <<= 1) {
                    unsigned long long o = __shfl_xor(lm, off, 64);
                    lm = (o > lm) ? o : lm;
                }
                if (lane == 0) {
                    int idx = (int)(0xFFFFFFFFu - (unsigned int)(lm & 0xFFFFFFFFull));
                    stci(&nbb[grow * KNB + pass], b * N1 + idx);
                }
#pragma unroll
                for (int t = 0; t < 16; ++t) if (k[t] == lm) k[t] = 0;
            }
        }
        // publish indb/nbb so this block's own plain reads see them
        asm volatile("s_waitcnt vmcnt(0)" ::: "memory");
        __syncthreads();
    };

    // ===== epoch 1: feat transpose (64 cols/block) + xyz0 gather =====
    if (P.tr) {
        const int g0 = blk * 64;
        const int col = tid & 63, rowH = tid >> 6;
        for (int c0 = 0; c0 < C_IN; c0 += 8) {
            int c = c0 + rowH;
            u.tt[col][c] = P.feat[(size_t)c * N_TOTAL + g0 + col];    // coalesced
        }
        __syncthreads();
        for (int i = tid; i < 64 * C_IN; i += BLOCK) {
            int cc = i >> 7, c = i & 127;
            stc(&P.featT[(size_t)(g0 + cc) * C_IN + c], u.tt[cc][c]); // coalesced
        }
    }
    if (tid < 16) {
        int j = blk * 16 + tid;
        int p = P.ind0[j];
        stc(&P.xyz0[j * 3 + 0], P.xyz[p * 3 + 0]);
        stc(&P.xyz0[j * 3 + 1], P.xyz[p * 3 + 1]);
        stc(&P.xyz0[j * 3 + 2], P.xyz[p * 3 + 2]);
    }
    BAR(1);

    // ===== stage 0 (16 nodes/block) =====
    sphere(16, P.ind0, P.wsS[0], P.bsS[0], P.xs0[0]);
    BAR(2);
    dgcn(16, P.xs0[0], P.nb0, P.dgWs[0], P.dgWn[0], P.dgB[0], 0, P.xs0[1], false, nullptr, nullptr, nullptr, nullptr);
    BAR(3);
    dgcn(16, P.xs0[1], P.nb0, P.dgWs[0], P.dgWn[0], P.dgB[0], 1, P.xs0[2], false, nullptr, nullptr, nullptr, nullptr);
    BAR(4);
    dgcn(16, P.xs0[2], P.nb0, P.dgWs[0], P.dgWn[0], P.dgB[0], 2, P.xs0[3], false, nullptr, nullptr, nullptr, nullptr);
    BAR(5);
    dgcn(16, P.xs0[3], P.nb0, P.dgWs[0], P.dgWn[0], P.dgB[0], 3, nullptr, true,
         P.dgH[0], P.dgHb[0], P.s0, P.out);

    // blocks >= NACT: permanently satisfy their slot and exit
    if (blk >= NACT) {
        asm volatile("s_waitcnt vmcnt(0)" ::: "memory");
        __syncthreads();
        if (tid == 0)
            __hip_atomic_store(&P.slot[blk], SLOT_DONE, __ATOMIC_RELAXED,
                               __HIP_MEMORY_SCOPE_AGENT);
        return;
    }
    BAR(6);

    // ===== NMS (block 0 only; s0/xyz0 plain — fresh lines) =====
    if (blk == 0) {
        for (int jj = tid; jj < N0; jj += BLOCK) u.sc[jj] = P.s0[jj];
        __syncthreads();
        for (int it = 0; it < 3; ++it) {
            float bv = -INFINITY; int bi = 0x7fffffff;
            for (int jj = tid; jj < N0; jj += BLOCK) {
                float v = u.sc[jj];
                if (v > bv) { bv = v; bi = jj; }   // strided ascending: first max kept
            }
            rv[tid] = bv; ri[tid] = bi;
            __syncthreads();
            for (int sft = BLOCK / 2; sft > 0; sft >>= 1) {
                if (tid < sft) {
                    float v2 = rv[tid + sft]; int i2 = ri[tid + sft];
                    if (v2 > rv[tid] || (v2 == rv[tid] && i2 < ri[tid])) {
                        rv[tid] = v2; ri[tid] = i2;
                    }
                }
                __syncthreads();
            }
            int sel = ri[0];
            if (tid == 0) {
                stci(&P.anchorA[it], P.ind0[sel]);
                psel[0] = P.xyz0[sel * 3 + 0];
                psel[1] = P.xyz0[sel * 3 + 1];
                psel[2] = P.xyz0[sel * 3 + 2];
            }
            __syncthreads();
            float px = psel[0], py = psel[1], pz = psel[2];
            for (int jj = tid; jj < N0; jj += BLOCK) {
                float d = fabsf(P.xyz0[jj * 3 + 0] * px + P.xyz0[jj * 3 + 1] * py
                              + P.xyz0[jj * 3 + 2] * pz);
                if (d >= COS_T) u.sc[jj] = NEG_INF;
            }
            __syncthreads();
        }
    }
    BAR(7);

    // ===== stages 1 & 2 (384 blocks x 8 nodes) =====
    for (int st = 1; st <= 2; ++st) {
        float* const* xb = (st == 1) ? P.xs1 : P.xs2;
        int* indb = (st == 1) ? P.indb1 : P.indb2;
        int* nbb  = (st == 1) ? P.nbb1  : P.nbb2;
        const int* anc = (st == 1) ? P.anchorA : P.anchorB;
        const int ep = (st == 1) ? 7 : 13;

        topk(P.isc[st - 1], anc, indb, nbb);
        sphere(8, indb, P.wsS[st], P.bsS[st], xb[0]);
        BAR(ep + 1);
        dgcn(8, xb[0], nbb, P.dgWs[st], P.dgWn[st], P.dgB[st], 0, xb[1], false, nullptr, nullptr, nullptr, nullptr);
        BAR(ep + 2);
        dgcn(8, xb[1], nbb, P.dgWs[st], P.dgWn[st], P.dgB[st], 1, xb[2], false, nullptr, nullptr, nullptr, nullptr);
        BAR(ep + 3);
        dgcn(8, xb[2], nbb, P.dgWs[st], P.dgWn[st], P.dgB[st], 2, xb[3], false, nullptr, nullptr, nullptr, nullptr);
        BAR(ep + 4);
        dgcn(8, xb[3], nbb, P.dgWs[st], P.dgWn[st], P.dgB[st], 3, nullptr, true,
             P.dgH[st], P.dgHb[st], (st == 1) ? P.sbr : nullptr,
             P.out + N0 + (st - 1) * 3 * N1);
        if (st == 1) {
            BAR(12);
            if (blk < 3) {    // per-branch argmax over sbr (plain, fresh)
                float bv = -INFINITY; int bi = 0x7fffffff;
                for (int m = tid; m < N1; m += BLOCK) {
                    float v = P.sbr[blk * N1 + m];
                    if (v > bv) { bv = v; bi = m; }   // ascending: first max kept
                }
                rv[tid] = bv; ri[tid] = bi;
                __syncthreads();
                for (int sft = BLOCK / 2; sft > 0; sft >>= 1) {
                    if (tid < sft) {
                        float v2 = rv[tid + sft]; int i2 = ri[tid + sft];
                        if (v2 > rv[tid] || (v2 == rv[tid] && i2 < ri[tid])) {
                            rv[tid] = v2; ri[tid] = i2;
                        }
                    }
                    __syncthreads();
                }
                if (tid == 0) stci(&P.anchorB[blk], P.indb1[blk * N1 + ri[0]]);
            }
            BAR(13);
        }
    }
}

extern "C" void kernel_launch(void* const* d_in, const int* in_sizes, int n_in,
                              void* d_out, int out_size, void* d_ws, size_t ws_size,
                              hipStream_t stream) {
    MegaParams hp;
    hp.feat = (const float*)d_in[0];
    hp.xyz  = (const float*)d_in[1];
    hp.wsS[0] = (const float*)d_in[2];  hp.bsS[0] = (const float*)d_in[3];
    hp.wsS[1] = (const float*)d_in[4];  hp.bsS[1] = (const float*)d_in[5];
    hp.wsS[2] = (const float*)d_in[6];  hp.bsS[2] = (const float*)d_in[7];
    hp.dgWs[0] = (const float*)d_in[8];  hp.dgWn[0] = (const float*)d_in[9];
    hp.dgB[0]  = (const float*)d_in[10]; hp.dgH[0]  = (const float*)d_in[11];
    hp.dgHb[0] = (const float*)d_in[12];
    hp.dgWs[1] = (const float*)d_in[13]; hp.dgWn[1] = (const float*)d_in[14];
    hp.dgB[1]  = (const float*)d_in[15]; hp.dgH[1]  = (const float*)d_in[16];
    hp.dgHb[1] = (const float*)d_in[17];
    hp.dgWs[2] = (const float*)d_in[18]; hp.dgWn[2] = (const float*)d_in[19];
    hp.dgB[2]  = (const float*)d_in[20]; hp.dgH[2]  = (const float*)d_in[21];
    hp.dgHb[2] = (const float*)d_in[22];
    const int* edge0 = (const int*)d_in[23];
    hp.nb0  = edge0 + N0 * KNB;
    hp.ind0 = (const int*)d_in[24];
    hp.isc[0] = (const int*)d_in[25];
    hp.isc[1] = (const int*)d_in[26];
    hp.out = (float*)d_out;

    float* f = (float*)d_ws;
    size_t o = 0;
    auto takeF = [&](size_t n) { float* p = f + o; o += n; return p; };

    hp.s0   = takeF(N0);
    hp.sbr  = takeF(3 * N1);
    hp.xyz0 = takeF((size_t)N0 * 3);
    o = (o + 63) & ~(size_t)63;
    hp.anchorA = (int*)takeF(64);
    hp.anchorB = (int*)takeF(64);
    hp.indb1 = (int*)takeF(3 * N1);
    hp.nbb1  = (int*)takeF(3 * N1 * KNB);
    hp.indb2 = (int*)takeF(3 * N1);
    hp.nbb2  = (int*)takeF(3 * N1 * KNB);
    o = (o + 63) & ~(size_t)63;
    hp.slot = (unsigned*)takeF(GRID);            // 512 arrival slots
    hp.flag = (unsigned*)takeF(8 * 16);          // 8 replicated flag lines
    unsigned* ctrBase = hp.slot;

    // activation buffers: distinct per phase if ws allows
    size_t needFast = (o + 4 * (size_t)N0 * C_H + 8 * (size_t)(3 * N1) * C_H) * sizeof(float);
    if (ws_size >= needFast) {
        hp.actCoh = 0;
        for (int i = 0; i < 4; ++i) hp.xs0[i] = takeF((size_t)N0 * C_H);
        for (int i = 0; i < 4; ++i) hp.xs1[i] = takeF((size_t)(3 * N1) * C_H);
        for (int i = 0; i < 4; ++i) hp.xs2[i] = takeF((size_t)(3 * N1) * C_H);
    } else {
        hp.actCoh = 1;
        float* xA = takeF((size_t)N0 * C_H);
        float* xB = takeF((size_t)N0 * C_H);
        for (int i = 0; i < 4; ++i) {
            hp.xs0[i] = (i & 1) ? xB : xA;
            hp.xs1[i] = (i & 1) ? xB : xA;
            hp.xs2[i] = (i & 1) ? xB : xA;
        }
    }

    // featT if it fits
    size_t needTr = (o + (size_t)N_TOTAL * C_IN) * sizeof(float);
    if (ws_size >= needTr) {
        hp.tr = 1;
        hp.featT = takeF((size_t)N_TOTAL * C_IN);
    } else {
        hp.tr = 0;
        hp.featT = nullptr;
    }

    hipMemsetAsync((void*)ctrBase, 0, (GRID + 8 * 16) * sizeof(unsigned), stream);
    mega_kernel<<<dim3(GRID), dim3(BLOCK), 0, stream>>>(hp);
}